// Round 2
// baseline (499.779 us; speedup 1.0000x reference)
//
#include <hip/hip_runtime.h>
#include <hip/hip_bf16.h>
#include <cstddef>

#define NVOX 32768
#define J5 5
#define NSLAB 4
#define SLABX 8            // x-values per slab
#define SLABV 8192         // voxels per slab = SLABX*32*32
typedef __hip_bfloat16 bf16;

// pe(pos, c): matches pos_enc(128, L) in f32:
// div = exp((c&~1) * (-ln(10000)/128)); even c -> sin(pos*div), odd -> cos
static __device__ __forceinline__ float pe_val(int pos, int c) {
  float dv = expf((float)(c & ~1) * (-0.0719557841560639f));
  float arg = (float)pos * dv;
  return (c & 1) ? cosf(arg) : sinf(arg);
}

// ---------- transpose triplane to channel-contiguous ----------
// tt[((b*3+seg)*1024 + cell)*64 + cc] = tp[((b*64+cc)*96 + seg*32 + (cell>>5))*32 + (cell&31)]
__global__ __launch_bounds__(256) void k_tri_t(const float* __restrict__ tp,
                                               float* __restrict__ tt, int total) {
  int idx = blockIdx.x * 256 + threadIdx.x;
  if (idx >= total) return;
  int cc   = idx & 63;
  int rem  = idx >> 6;
  int cell = rem & 1023;
  int segb = rem >> 10;          // b*3+seg
  int seg = segb % 3, b = segb / 3;
  int i = cell >> 5, j = cell & 31;
  tt[idx] = tp[(((size_t)(b * 64 + cc)) * 96 + seg * 32 + i) * 32 + j];
}

// ---------- fold weights ----------
__global__ __launch_bounds__(256) void k_fold(
    const float* __restrict__ in_w, const float* __restrict__ in_b,
    const float* __restrict__ q_w, const float* __restrict__ q_b,
    const float* __restrict__ proj_w, const float* __restrict__ out_w,
    const float* __restrict__ out_b, const float* __restrict__ proj_b,
    float* __restrict__ Wqc, float* __restrict__ qcb,
    float* __restrict__ Wo, float* __restrict__ obb) {
  int idx = blockIdx.x * 256 + threadIdx.x;
  if (idx < 128 * 192) {
    int c = idx / 192, k = idx % 192;
    float s = 0.f;
    for (int j = 0; j < 128; j++) s = fmaf(in_w[c * 128 + j], q_w[j * 192 + k], s);
    Wqc[idx] = s;
  } else if (idx < 128 * 192 + 128) {
    int c = idx - 128 * 192;
    float s = in_b[c];
    for (int j = 0; j < 128; j++) s = fmaf(in_w[c * 128 + j], q_b[j], s);
    qcb[c] = s;
  } else if (idx < 128 * 192 + 128 + 64 * 128) {
    int e = idx - (128 * 192 + 128);
    int o = e / 128, c = e % 128;
    float s = 0.f;
    for (int j = 0; j < 128; j++) s = fmaf(proj_w[o * 128 + j], out_w[j * 128 + c], s);
    Wo[e] = s;
  } else if (idx < 128 * 192 + 128 + 64 * 128 + 64) {
    int o = idx - (128 * 192 + 128 + 64 * 128);
    float s = proj_b[o];
    for (int j = 0; j < 128; j++) s = fmaf(proj_w[o * 128 + j], out_b[j], s);
    obb[o] = s;
  }
}

// ---------- stage1: kfeat/vfeat = img @ {k_w,v_w}.T + bias + pe_img ----------
// 8 img rows per block; img rows are block-uniform -> scalar loads; weight row per lane.
__global__ __launch_bounds__(128) void k_kvfeat(
    const float* __restrict__ img, const float* __restrict__ kw, const float* __restrict__ kb,
    const float* __restrict__ vw, const float* __restrict__ vb,
    float* __restrict__ kf, float* __restrict__ vf) {
  int which = blockIdx.y;
  const float* w    = which ? vw : kw;
  const float* bias = which ? vb : kb;
  float* outp       = which ? vf : kf;
  int row0 = blockIdx.x * 8;          // 8 | 256 so never straddles a (b,j) image
  int c = threadIdx.x;
  const float* wr = w + (size_t)c * 1280;
  int bj = row0 >> 8, p0 = row0 & 255;
  const float* ibase = img + ((size_t)(bj * 257 + 1 + p0)) * 1280;  // skip cls token
  float acc[8] = {0, 0, 0, 0, 0, 0, 0, 0};
  for (int k = 0; k < 1280; k += 4) {
    float4 w4 = *(const float4*)(wr + k);
#pragma unroll
    for (int r = 0; r < 8; r++) {
      float4 iv = *(const float4*)(ibase + (size_t)r * 1280 + k);
      acc[r] = fmaf(iv.w, w4.w, fmaf(iv.z, w4.z, fmaf(iv.y, w4.y, fmaf(iv.x, w4.x, acc[r]))));
    }
  }
  float bc = bias[c];
#pragma unroll
  for (int r = 0; r < 8; r++)
    outp[(size_t)(row0 + r) * 128 + c] = acc[r] + bc + pe_val(p0 + r, c);
}

// ---------- stage2: k2/v2 = {kfeat,vfeat} @ {Wk,Wv}.T + {bk,bv} ----------
__global__ __launch_bounds__(128) void k_kv2(
    const float* __restrict__ kf, const float* __restrict__ vf,
    const float* __restrict__ in_w, const float* __restrict__ in_b,
    float* __restrict__ k2, float* __restrict__ v2) {
  int which = blockIdx.y;
  const float* src = which ? vf : kf;
  float* dst       = which ? v2 : k2;
  const float* W  = in_w + (size_t)(128 + which * 128) * 128;
  const float* bb = in_b + 128 + which * 128;
  int r0 = blockIdx.x * 8;
  int c = threadIdx.x;
  const float* wr = W + (size_t)c * 128;
  float acc[8] = {0, 0, 0, 0, 0, 0, 0, 0};
  for (int k = 0; k < 128; k += 4) {
    float4 w4 = *(const float4*)(wr + k);
#pragma unroll
    for (int r = 0; r < 8; r++) {
      float4 f4 = *(const float4*)(src + (size_t)(r0 + r) * 128 + k);
      acc[r] = fmaf(f4.w, w4.w, fmaf(f4.z, w4.z, fmaf(f4.y, w4.y, fmaf(f4.x, w4.x, acc[r]))));
    }
  }
  float bc = bb[c];
#pragma unroll
  for (int r = 0; r < 8; r++) dst[(size_t)(r0 + r) * 128 + c] = acc[r] + bc;
}

// ---------- qbias slab: qb[nl][c] = pe(n) . Wq[c] + qcb[c], bf16 ----------
__global__ __launch_bounds__(128) void k_qbias(
    const float* __restrict__ in_w, const float* __restrict__ qcb,
    bf16* __restrict__ qb, int s) {
  __shared__ __align__(16) float pe_lds[4][128];
  int n0l = blockIdx.x * 4;
  int t = threadIdx.x;
  {
    int r = t >> 5, kk = t & 31;
    int n = s * SLABV + n0l + r;
#pragma unroll
    for (int u = 0; u < 4; u++) {
      int c = kk * 4 + u;
      pe_lds[r][c] = pe_val(n, c);
    }
  }
  __syncthreads();
  int c = t;
  const float* wr = in_w + (size_t)c * 128;   // Wq row c
  float a0 = 0, a1 = 0, a2 = 0, a3 = 0;
  for (int k = 0; k < 128; k += 4) {
    float4 w4 = *(const float4*)(wr + k);
    float4 p0 = *(const float4*)(&pe_lds[0][k]);
    float4 p1 = *(const float4*)(&pe_lds[1][k]);
    float4 p2 = *(const float4*)(&pe_lds[2][k]);
    float4 p3 = *(const float4*)(&pe_lds[3][k]);
    a0 = fmaf(p0.w, w4.w, fmaf(p0.z, w4.z, fmaf(p0.y, w4.y, fmaf(p0.x, w4.x, a0))));
    a1 = fmaf(p1.w, w4.w, fmaf(p1.z, w4.z, fmaf(p1.y, w4.y, fmaf(p1.x, w4.x, a1))));
    a2 = fmaf(p2.w, w4.w, fmaf(p2.z, w4.z, fmaf(p2.y, w4.y, fmaf(p2.x, w4.x, a2))));
    a3 = fmaf(p3.w, w4.w, fmaf(p3.z, w4.z, fmaf(p3.y, w4.y, fmaf(p3.x, w4.x, a3))));
  }
  float qc = qcb[c];
  qb[(size_t)(n0l + 0) * 128 + c] = __float2bfloat16(a0 + qc);
  qb[(size_t)(n0l + 1) * 128 + c] = __float2bfloat16(a1 + qc);
  qb[(size_t)(n0l + 2) * 128 + c] = __float2bfloat16(a2 + qc);
  qb[(size_t)(n0l + 3) * 128 + c] = __float2bfloat16(a3 + qc);
}

// ---------- fused main (one slab, both batches): qh GEMM + proj + sample + attention ----------
__global__ __launch_bounds__(128) void k_main(
    const float* __restrict__ tri_t, const bf16* __restrict__ qb,
    const float* __restrict__ Wqc, const float* __restrict__ k2,
    const float* __restrict__ v2, const float* __restrict__ proj,
    bf16* __restrict__ obuf, int s) {
  __shared__ __align__(16) float qh[16 * 128];
  __shared__ __align__(16) int   sI[16 * J5][4];
  __shared__ __align__(16) float sW[16 * J5][4];
  __shared__ __align__(16) float lg[16 * J5 * 8];
  const int b   = blockIdx.y;
  const int nl0 = blockIdx.x * 16;          // local voxel base within slab
  const int n0  = s * SLABV + nl0;          // global voxel base
  const int t   = threadIdx.x;

  int cell0[16], cell1[16], cell2[16];
#pragma unroll
  for (int r = 0; r < 16; r++) {
    int n = n0 + r;
    int x = n >> 10, y = (n >> 5) & 31, z = n & 31;
    cell0[r] = z * 32 + x;   // xz
    cell1[r] = y * 32 + x;   // xy
    cell2[r] = z * 32 + y;   // yz
  }
  const float* base0 = tri_t + ((size_t)(b * 3 + 0)) * 1024 * 64;
  const float* base1 = tri_t + ((size_t)(b * 3 + 1)) * 1024 * 64;
  const float* base2 = tri_t + ((size_t)(b * 3 + 2)) * 1024 * 64;

  // phase B: qh[r][c] = tri[r] . Wqc[c] + qb[n][c]
  {
    const int c = t;
    float acc[16];
#pragma unroll
    for (int r = 0; r < 16; r++) acc[r] = __bfloat162float(qb[(size_t)(nl0 + r) * 128 + c]);
    const float* wr = Wqc + (size_t)c * 192;
    for (int kt = 0; kt < 64; kt += 4) {
      float4 w4 = *(const float4*)(wr + kt);
#pragma unroll
      for (int r = 0; r < 16; r++) {
        float4 t4 = *(const float4*)(base0 + (size_t)cell0[r] * 64 + kt);
        acc[r] = fmaf(t4.w, w4.w, fmaf(t4.z, w4.z, fmaf(t4.y, w4.y, fmaf(t4.x, w4.x, acc[r]))));
      }
    }
    for (int kt = 0; kt < 64; kt += 4) {
      float4 w4 = *(const float4*)(wr + 64 + kt);
#pragma unroll
      for (int r = 0; r < 16; r++) {
        float4 t4 = *(const float4*)(base1 + (size_t)cell1[r] * 64 + kt);
        acc[r] = fmaf(t4.w, w4.w, fmaf(t4.z, w4.z, fmaf(t4.y, w4.y, fmaf(t4.x, w4.x, acc[r]))));
      }
    }
    for (int kt = 0; kt < 64; kt += 4) {
      float4 w4 = *(const float4*)(wr + 128 + kt);
#pragma unroll
      for (int r = 0; r < 16; r++) {
        float4 t4 = *(const float4*)(base2 + (size_t)cell2[r] * 64 + kt);
        acc[r] = fmaf(t4.w, w4.w, fmaf(t4.z, w4.z, fmaf(t4.y, w4.y, fmaf(t4.x, w4.x, acc[r]))));
      }
    }
#pragma unroll
    for (int r = 0; r < 16; r++) qh[r * 128 + c] = acc[r];
  }

  // phase C: projection + bilinear taps (t < 80)
  if (t < 16 * J5) {
    int r = t / J5, j = t % J5;
    int n = n0 + r;
    int x = n >> 10, y = (n >> 5) & 31, z = n & 31;
    const float SC = (float)(1.0 + 0.1 + 1e-05);
    float fx = ((float)x / 31.0f - 0.5f) * 2.0f * SC;
    float fy = ((float)y / 31.0f - 0.5f) * 2.0f * SC;
    float fz = ((float)z / 31.0f - 0.5f) * 2.0f * SC;
    const float* P = proj + (size_t)(b * J5 + j) * 16;
    float pc0 = fmaf(fx, P[0], fmaf(fy, P[1], fmaf(fz, P[2],  P[3])));
    float pc1 = fmaf(fx, P[4], fmaf(fy, P[5], fmaf(fz, P[6],  P[7])));
    float pc2 = fmaf(fx, P[8], fmaf(fy, P[9], fmaf(fz, P[10], P[11])));
    float px = pc0 / pc2, py = pc1 / pc2;
    float gx = fminf(fmaxf((px / 223.0f - 0.5f) * 2.0f, -1.0f), 1.0f);
    float gy = fminf(fmaxf((py / 223.0f - 0.5f) * 2.0f, -1.0f), 1.0f);
    float ux = (gx + 1.0f) * 0.5f * 15.0f;
    float uy = (gy + 1.0f) * 0.5f * 15.0f;
    float fx0 = floorf(ux), fy0 = floorf(uy);
    int x0 = (int)fx0, y0 = (int)fy0;
    float wx = ux - fx0, wy = uy - fy0;
    int x1 = min(x0 + 1, 15), y1 = min(y0 + 1, 15);
    x0 = min(max(x0, 0), 15); y0 = min(max(y0, 0), 15);
    int rowb = (b * J5 + j) * 256;
    sI[t][0] = (rowb + y0 * 16 + x0) * 128;
    sI[t][1] = (rowb + y0 * 16 + x1) * 128;
    sI[t][2] = (rowb + y1 * 16 + x0) * 128;
    sI[t][3] = (rowb + y1 * 16 + x1) * 128;
    sW[t][0] = (1.f - wx) * (1.f - wy);
    sW[t][1] = wx * (1.f - wy);
    sW[t][2] = (1.f - wx) * wy;
    sW[t][3] = wx * wy;
  }
  __syncthreads();

  // phase D: logits via 16-lane shfl reduce
  {
    const int c = t;
    const int h = c >> 4;
    for (int rj = 0; rj < 16 * J5; rj++) {
      int r = rj / J5;
      int4   i4 = *(const int4*)sI[rj];
      float4 w4 = *(const float4*)sW[rj];
      float kh = w4.x * k2[i4.x + c] + w4.y * k2[i4.y + c]
               + w4.z * k2[i4.z + c] + w4.w * k2[i4.w + c];
      float pv = qh[r * 128 + c] * kh;
      pv += __shfl_xor(pv, 1, 16);
      pv += __shfl_xor(pv, 2, 16);
      pv += __shfl_xor(pv, 4, 16);
      pv += __shfl_xor(pv, 8, 16);
      if ((c & 15) == 0) lg[rj * 8 + h] = pv * 0.25f;
    }
  }
  __syncthreads();

  // phase E: softmax over j per (r, h)
  {
    int r = t >> 3, h = t & 7;
    float l[J5];
    float m = -1e30f;
#pragma unroll
    for (int j = 0; j < J5; j++) { l[j] = lg[(r * J5 + j) * 8 + h]; m = fmaxf(m, l[j]); }
    float sden = 0.f;
#pragma unroll
    for (int j = 0; j < J5; j++) { l[j] = expf(l[j] - m); sden += l[j]; }
    float inv = 1.0f / sden;
#pragma unroll
    for (int j = 0; j < J5; j++) lg[(r * J5 + j) * 8 + h] = l[j] * inv;
  }
  __syncthreads();

  // phase F: o[r][c] = sum_j attn * vh ; write obuf (bf16)
  {
    const int c = t, h = c >> 4;
    for (int r = 0; r < 16; r++) {
      float o = 0.f;
      for (int j = 0; j < J5; j++) {
        int rj = r * J5 + j;
        int4   i4 = *(const int4*)sI[rj];
        float4 w4 = *(const float4*)sW[rj];
        float vh = w4.x * v2[i4.x + c] + w4.y * v2[i4.y + c]
                 + w4.z * v2[i4.z + c] + w4.w * v2[i4.w + c];
        o = fmaf(lg[rj * 8 + h], vh, o);
      }
      obuf[((size_t)b * SLABV + nl0 + r) * 128 + c] = __float2bfloat16(o);
    }
  }
}

// ---------- per-slab plane reductions (raw sums; /32 folded into k_final) ----------
__global__ __launch_bounds__(128) void k_reduce(const bf16* __restrict__ obuf,
                                                float* __restrict__ pacc, int s) {
  int idx = blockIdx.x;     // 0..1535
  int b = blockIdx.y;
  int c = threadIdx.x;
  const bf16* ob = obuf + (size_t)b * SLABV * 128;
  if (idx < 256) {          // xz plane: row=z, col=x ; sum over y (complete in slab)
    int z = idx >> 3, xl = idx & 7;
    float sum = 0.f;
    for (int y = 0; y < 32; y++)
      sum += __bfloat162float(ob[(size_t)(xl * 1024 + y * 32 + z) * 128 + c]);
    pacc[((size_t)(b * 96 + z) * 32 + s * SLABX + xl) * 128 + c] = sum;
  } else if (idx < 512) {   // xy plane: row=y, col=x ; sum over z (complete in slab)
    int e = idx - 256;
    int y = e >> 3, xl = e & 7;
    float sum = 0.f;
    for (int z = 0; z < 32; z++)
      sum += __bfloat162float(ob[(size_t)(xl * 1024 + y * 32 + z) * 128 + c]);
    pacc[((size_t)(b * 96 + 32 + y) * 32 + s * SLABX + xl) * 128 + c] = sum;
  } else {                  // yz plane: row=z, col=y ; partial over x, accumulate across slabs
    int e = idx - 512;
    int z = e >> 5, y = e & 31;
    float sum = 0.f;
    for (int xl = 0; xl < SLABX; xl++)
      sum += __bfloat162float(ob[(size_t)(xl * 1024 + y * 32 + z) * 128 + c]);
    size_t pi = ((size_t)(b * 96 + 64 + z) * 32 + y) * 128 + c;
    pacc[pi] = (s == 0) ? sum : (pacc[pi] + sum);
  }
}

// ---------- final projection ----------
__global__ __launch_bounds__(128) void k_final(
    const float* __restrict__ pacc, const float* __restrict__ Wo,
    const float* __restrict__ obb, float* __restrict__ outp) {
  int bp = blockIdx.x;            // b*96 + prow
  int b = bp / 96, prow = bp % 96;
  int obase = blockIdx.y * 16;
  __shared__ __align__(16) float lds[32 * 129];
  for (int idx = threadIdx.x; idx < 4096; idx += 128) {
    int col = idx >> 7, k = idx & 127;
    lds[col * 129 + k] = pacc[(size_t)bp * 32 * 128 + idx] * (1.0f / 32.0f);
  }
  __syncthreads();
  for (int e = threadIdx.x; e < 16 * 32; e += 128) {
    int o = obase + (e >> 5), col = e & 31;
    float val = obb[o];
    const float* wr = Wo + (size_t)o * 128;
    const float* lr = lds + col * 129;
    for (int k = 0; k < 128; k++) val = fmaf(wr[k], lr[k], val);
    outp[((size_t)(b * 64 + o) * 96 + prow) * 32 + col] = val;
  }
}

extern "C" void kernel_launch(void* const* d_in, const int* in_sizes, int n_in,
                              void* d_out, int out_size, void* d_ws, size_t ws_size,
                              hipStream_t stream) {
  const float* tp     = (const float*)d_in[0];
  const float* img    = (const float*)d_in[1];
  const float* proj   = (const float*)d_in[2];
  const float* k_w    = (const float*)d_in[4];
  const float* k_b    = (const float*)d_in[5];
  const float* q_w    = (const float*)d_in[6];
  const float* q_b    = (const float*)d_in[7];
  const float* v_w    = (const float*)d_in[8];
  const float* v_b    = (const float*)d_in[9];
  const float* in_w   = (const float*)d_in[10];
  const float* in_b   = (const float*)d_in[11];
  const float* out_w  = (const float*)d_in[12];
  const float* out_b  = (const float*)d_in[13];
  const float* proj_w = (const float*)d_in[14];
  const float* proj_b = (const float*)d_in[15];
  const int B = 2, J = 5;

  // workspace layout (floats) — total 3,440,832 floats = 13,763,328 bytes
  float* ws = (float*)d_ws;
  size_t off = 0;
  float* tri_t = ws + off; off += (size_t)B * 3 * 1024 * 64;   // 393216
  float* k2    = ws + off; off += (size_t)B * J * 256 * 128;   // 327680
  float* v2    = ws + off; off += (size_t)B * J * 256 * 128;   // 327680
  float* Wqc   = ws + off; off += 128 * 192;                   // 24576
  float* qcb   = ws + off; off += 128;
  float* Wo    = ws + off; off += 64 * 128;
  float* obb   = ws + off; off += 64;
  float* pacc  = ws + off; off += (size_t)B * 96 * 32 * 128;   // 786432
  float* alias = ws + off;
  bf16*  qb    = (bf16*)alias;                                 // SLABV*128 bf16 = 524288 fslots
  bf16*  obuf  = (bf16*)(alias + (size_t)SLABV * 128 / 2);     // B*SLABV*128 bf16 = 1048576 fslots
  float* kfeat = alias;                                        // early alias (dead before qb/obuf written)
  float* vfeat = alias + (size_t)B * J * 256 * 128;
  off += (size_t)SLABV * 128 / 2 + (size_t)B * SLABV * 128 / 2;
  size_t needed_bytes = off * sizeof(float);
  if (ws_size < needed_bytes) return;   // diagnostic: absmax will read ~2.25e-2 (stub-like), no fault

  int totalT = B * 3 * 1024 * 64;
  k_tri_t<<<dim3((totalT + 255) / 256), dim3(256), 0, stream>>>(tp, tri_t, totalT);
  k_fold<<<dim3(129), dim3(256), 0, stream>>>(
      in_w, in_b, q_w, q_b, proj_w, out_w, out_b, proj_b, Wqc, qcb, Wo, obb);
  k_kvfeat<<<dim3(B * J * 256 / 8, 2), dim3(128), 0, stream>>>(img, k_w, k_b, v_w, v_b, kfeat, vfeat);
  k_kv2<<<dim3(B * J * 256 / 8, 2), dim3(128), 0, stream>>>(kfeat, vfeat, in_w, in_b, k2, v2);
  for (int s = 0; s < NSLAB; s++) {
    k_qbias<<<dim3(SLABV / 4), dim3(128), 0, stream>>>(in_w, qcb, qb, s);
    k_main<<<dim3(SLABV / 16, B), dim3(128), 0, stream>>>(tri_t, qb, Wqc, k2, v2, proj, obuf, s);
    k_reduce<<<dim3(1536, B), dim3(128), 0, stream>>>(obuf, pacc, s);
  }
  k_final<<<dim3(B * 96, 4), dim3(128), 0, stream>>>(pacc, Wo, obb, (float*)d_out);
}

// Round 3
// 256.842 us; speedup vs baseline: 1.9459x; 1.9459x over previous
//
#include <hip/hip_runtime.h>
#include <hip/hip_bf16.h>
#include <cstddef>

#define NVOX 32768
#define J5 5
#define NSLAB 4
#define SLABX 8
#define SLABV 8192
typedef __hip_bfloat16 bf16;
typedef __attribute__((ext_vector_type(8))) short bf16x8v;
typedef __attribute__((ext_vector_type(4))) float f32x4;

static __device__ __forceinline__ float pe_val(int pos, int c) {
  float dv = expf((float)(c & ~1) * (-0.0719557841560639f));
  float arg = (float)pos * dv;
  return (c & 1) ? cosf(arg) : sinf(arg);
}
static __device__ __forceinline__ short f2b(float f) {
  __hip_bfloat16 h = __float2bfloat16(f);
  return *reinterpret_cast<short*>(&h);
}
static __device__ __forceinline__ float b2f(short s) {
  __hip_bfloat16 h = *reinterpret_cast<__hip_bfloat16*>(&s);
  return __bfloat162float(h);
}
static __device__ __forceinline__ float2 cmul(float2 a, float2 b) {
  return make_float2(a.x * b.x - a.y * b.y, a.x * b.y + a.y * b.x);
}

// ---------- prep_small: complex tables, pe_img, in_wT, Wqb pe-part ----------
__global__ __launch_bounds__(256) void k_prep_small(
    const float* __restrict__ in_w, float2* __restrict__ tabs,
    float* __restrict__ pe_img, float* __restrict__ in_wT, short* __restrict__ Wqb_s) {
  int idx = blockIdx.x * 256 + threadIdx.x;
  if (idx < 6144) {                       // tabs: 3 tables x 32 pos x 64 i
    int tb = idx >> 11, rem = idx & 2047;
    int pos = rem >> 6, i = rem & 63;
    float dv = expf((float)(2 * i) * (-0.0719557841560639f));
    float mult = (tb == 0) ? 1024.0f : (tb == 1) ? 32.0f : 1.0f;
    float ang = (float)pos * mult * dv;
    tabs[idx] = make_float2(cosf(ang), sinf(ang));
  } else if (idx < 6144 + 32768) {        // pe_img[256][128]
    int e = idx - 6144;
    int p = e >> 7, c = e & 127;
    pe_img[e] = pe_val(p, c);
  } else if (idx < 6144 + 65536) {        // in_wT[j][256] = in_w[128+cc][j]
    int e = idx - (6144 + 32768);
    int j = e >> 8, cc = e & 255;
    in_wT[e] = in_w[(size_t)(128 + cc) * 128 + j];
  } else if (idx < 6144 + 65536 + 16384) { // Wqb pe-part: Wqb[c][192+j] = Wq[c][j]
    int e = idx - (6144 + 65536);
    int c = e >> 7, j = e & 127;
    Wqb_s[(size_t)c * 320 + 192 + j] = f2b(in_w[(size_t)c * 128 + j]);
  }
}

// ---------- img -> bf16 (skip cls token) ----------
__global__ __launch_bounds__(256) void k_cvt_img(const float* __restrict__ img,
                                                 short* __restrict__ imgb) {
  int e8 = blockIdx.x * 256 + threadIdx.x;   // 2560*160 units of 8
  int row = e8 / 160, k8 = e8 % 160;
  int bj = row >> 8, p = row & 255;
  const float* src = img + ((size_t)(bj * 257 + 1 + p)) * 1280 + k8 * 8;
  float4 a = *(const float4*)src;
  float4 b = *(const float4*)(src + 4);
  bf16x8v v;
  v[0] = f2b(a.x); v[1] = f2b(a.y); v[2] = f2b(a.z); v[3] = f2b(a.w);
  v[4] = f2b(b.x); v[5] = f2b(b.y); v[6] = f2b(b.z); v[7] = f2b(b.w);
  *reinterpret_cast<bf16x8v*>(imgb + (size_t)row * 1280 + k8 * 8) = v;
}

// ---------- triplane transpose -> bf16 channel-contiguous ----------
__global__ __launch_bounds__(256) void k_tri_tb(const float* __restrict__ tp,
                                                short* __restrict__ tt, int total) {
  int idx = blockIdx.x * 256 + threadIdx.x;
  if (idx >= total) return;
  int cc   = idx & 63;
  int rem  = idx >> 6;
  int cell = rem & 1023;
  int segb = rem >> 10;
  int seg = segb % 3, b = segb / 3;
  int i = cell >> 5, j = cell & 31;
  tt[idx] = f2b(tp[(((size_t)(b * 64 + cc)) * 96 + seg * 32 + i) * 32 + j]);
}

// ---------- Wkvb[c][k] = sum_j in_w[128+c][j] * {k_w,v_w}[j][k], bf16 ----------
__global__ __launch_bounds__(256) void k_fold_w(
    const float* __restrict__ in_w, const float* __restrict__ kw,
    const float* __restrict__ vw, short* __restrict__ Wkvb_s) {
  int k = blockIdx.x * 256 + threadIdx.x;   // <1280
  int c = blockIdx.y;                        // <256
  const float* w = (c < 128) ? kw : vw;
  const float* ir = in_w + (size_t)(128 + c) * 128;
  float acc = 0.f;
  for (int j = 0; j < 128; j++) acc = fmaf(ir[j], w[(size_t)j * 1280 + k], acc);
  Wkvb_s[(size_t)c * 1280 + k] = f2b(acc);
}

// ---------- misc folds: Wqc part of Wqb, peb, Wo, qcb/obb ----------
__global__ __launch_bounds__(192) void k_fold_misc(
    const float* __restrict__ in_w, const float* __restrict__ in_b,
    const float* __restrict__ q_w, const float* __restrict__ q_b,
    const float* __restrict__ k_b, const float* __restrict__ v_b,
    const float* __restrict__ proj_w, const float* __restrict__ out_w,
    const float* __restrict__ out_b, const float* __restrict__ proj_b,
    const float* __restrict__ pe_img, const float* __restrict__ in_wT,
    short* __restrict__ Wqb_s, float* __restrict__ peb,
    float* __restrict__ Wo, float* __restrict__ qcb, float* __restrict__ obb) {
  int bx = blockIdx.x, t = threadIdx.x;
  if (bx < 128) {                       // Wqc: Wqb[c][k] k<192
    int c = bx, k = t;
    const float* ir = in_w + (size_t)c * 128;
    float acc = 0.f;
    for (int j = 0; j < 128; j++) acc = fmaf(ir[j], q_w[(size_t)j * 192 + k], acc);
    Wqb_s[(size_t)c * 320 + k] = f2b(acc);
  } else if (bx < 128 + 512) {          // peb[which][p][c]
    if (t >= 128) return;
    int e = bx - 128;
    int which = e >> 8, p = e & 255, c = t;
    const float* bias = which ? v_b : k_b;
    float acc = in_b[128 + which * 128 + c];
    for (int j = 0; j < 128; j++)
      acc = fmaf(bias[j] + pe_img[(size_t)p * 128 + j], in_wT[(size_t)j * 256 + which * 128 + c], acc);
    peb[((size_t)(which * 256 + p)) * 128 + c] = acc;
  } else if (bx < 128 + 512 + 64) {     // Wo[o][c]
    if (t >= 128) return;
    int o = bx - 640, c = t;
    const float* pr = proj_w + (size_t)o * 128;
    float acc = 0.f;
    for (int j = 0; j < 128; j++) acc = fmaf(pr[j], out_w[(size_t)j * 128 + c], acc);
    Wo[(size_t)o * 128 + c] = acc;
  } else {                              // qcb / obb
    if (t < 128) {
      float acc = in_b[t];
      const float* ir = in_w + (size_t)t * 128;
      for (int j = 0; j < 128; j++) acc = fmaf(ir[j], q_b[j], acc);
      qcb[t] = acc;
    }
    if (t < 64) {
      float acc = proj_b[t];
      const float* pr = proj_w + (size_t)t * 128;
      for (int j = 0; j < 128; j++) acc = fmaf(pr[j], out_b[j], acc);
      obb[t] = acc;
    }
  }
}

// ---------- MFMA GEMM: k2v2[2560][256] = imgb @ Wkvb^T + peb ----------
__global__ __launch_bounds__(256) void k_gemm_kv(
    const short* __restrict__ imgb, const short* __restrict__ Wkvb_s,
    const float* __restrict__ peb, short* __restrict__ k2b, short* __restrict__ v2b) {
  __shared__ __align__(16) short A_lds[64 * 64];
  __shared__ __align__(16) short B_lds[64 * 64];
  const int m0 = blockIdx.x * 64;
  const int nb0 = blockIdx.y * 64;
  const int t = threadIdx.x;
  const int lane = t & 63, w = t >> 6;
  f32x4 acc[4];
#pragma unroll
  for (int f = 0; f < 4; f++) acc[f] = (f32x4){0.f, 0.f, 0.f, 0.f};

  for (int ct = 0; ct < 20; ct++) {
    __syncthreads();
#pragma unroll
    for (int it = 0; it < 2; it++) {
      int u = it * 256 + t;
      int r = u >> 3, g = u & 7;
      // A: imgb row m0+r, k chunk
      {
        const int4 src = *reinterpret_cast<const int4*>(imgb + (size_t)(m0 + r) * 1280 + ct * 64 + g * 8);
        *reinterpret_cast<int4*>(&A_lds[(r * 8 + (g ^ (r & 7))) * 8]) = src;
      }
      // B: Wkvb row nb0+r
      {
        const int4 src = *reinterpret_cast<const int4*>(Wkvb_s + (size_t)(nb0 + r) * 1280 + ct * 64 + g * 8);
        *reinterpret_cast<int4*>(&B_lds[(r * 8 + (g ^ (r & 7))) * 8]) = src;
      }
    }
    __syncthreads();
#pragma unroll
    for (int ks = 0; ks < 2; ks++) {
      int arow = w * 16 + (lane & 15);
      int akb = ks * 4 + (lane >> 4);
      bf16x8v a = *reinterpret_cast<const bf16x8v*>(&A_lds[(arow * 8 + (akb ^ (arow & 7))) * 8]);
#pragma unroll
      for (int f = 0; f < 4; f++) {
        int bcol = f * 16 + (lane & 15);
        bf16x8v bb = *reinterpret_cast<const bf16x8v*>(&B_lds[(bcol * 8 + (akb ^ (bcol & 7))) * 8]);
        acc[f] = __builtin_amdgcn_mfma_f32_16x16x32_bf16(a, bb, acc[f], 0, 0, 0);
      }
    }
  }
  // epilogue
#pragma unroll
  for (int f = 0; f < 4; f++) {
#pragma unroll
    for (int reg = 0; reg < 4; reg++) {
      int grow = m0 + w * 16 + (lane >> 4) * 4 + reg;
      int gcol = nb0 + f * 16 + (lane & 15);
      int p = grow & 255;
      int which = gcol >> 7, c = gcol & 127;
      float val = acc[f][reg] + peb[((size_t)(which * 256 + p)) * 128 + c];
      short* dst = which ? v2b : k2b;
      dst[(size_t)grow * 128 + c] = f2b(val);
    }
  }
}

// ---------- fused main: MFMA q-GEMM (tri|pe stacked) + proj + sample + attention ----------
__global__ __launch_bounds__(256) void k_main(
    const short* __restrict__ tri_tb, const short* __restrict__ Wqb_s,
    const float* __restrict__ qcb, const float2* __restrict__ tabs,
    const short* __restrict__ k2b, const short* __restrict__ v2b,
    const float* __restrict__ proj, bf16* __restrict__ obuf, int s) {
  __shared__ __align__(16) short A_lds[32 * 64];
  __shared__ __align__(16) short B_lds[128 * 64];
  __shared__ __align__(16) short qh_lds[32 * 128];
  __shared__ __align__(16) ushort sIr[160][4];
  __shared__ __align__(16) float sW4[160][4];
  __shared__ __align__(16) float lg[160 * 8];
  const int b = blockIdx.y;
  const int nl0 = blockIdx.x * 32;
  const int n0 = s * SLABV + nl0;
  const int t = threadIdx.x;
  const int lane = t & 63, w = t >> 6;
  const int xq = n0 >> 10, yq = (n0 >> 5) & 31;   // uniform over block (32 | n0)
  const float2* tabX = tabs;
  const float2* tabY = tabs + 2048;
  const float2* tabZ = tabs + 4096;

  // phase C: projection + bilinear taps
  if (t < 160) {
    int r = t / J5, j = t % J5;
    int n = n0 + r;
    int x = n >> 10, y = (n >> 5) & 31, z = n & 31;
    const float SC = (float)(1.0 + 0.1 + 1e-05);
    float fx = ((float)x / 31.0f - 0.5f) * 2.0f * SC;
    float fy = ((float)y / 31.0f - 0.5f) * 2.0f * SC;
    float fz = ((float)z / 31.0f - 0.5f) * 2.0f * SC;
    const float* P = proj + (size_t)(b * J5 + j) * 16;
    float pc0 = fmaf(fx, P[0], fmaf(fy, P[1], fmaf(fz, P[2],  P[3])));
    float pc1 = fmaf(fx, P[4], fmaf(fy, P[5], fmaf(fz, P[6],  P[7])));
    float pc2 = fmaf(fx, P[8], fmaf(fy, P[9], fmaf(fz, P[10], P[11])));
    float px = pc0 / pc2, py = pc1 / pc2;
    float gx = fminf(fmaxf((px / 223.0f - 0.5f) * 2.0f, -1.0f), 1.0f);
    float gy = fminf(fmaxf((py / 223.0f - 0.5f) * 2.0f, -1.0f), 1.0f);
    float ux = (gx + 1.0f) * 0.5f * 15.0f;
    float uy = (gy + 1.0f) * 0.5f * 15.0f;
    float fx0 = floorf(ux), fy0 = floorf(uy);
    int x0 = (int)fx0, y0 = (int)fy0;
    float wx = ux - fx0, wy = uy - fy0;
    int x1 = min(x0 + 1, 15), y1 = min(y0 + 1, 15);
    x0 = min(max(x0, 0), 15); y0 = min(max(y0, 0), 15);
    int rowb = (b * J5 + j) * 256;
    sIr[t][0] = (ushort)(rowb + y0 * 16 + x0);
    sIr[t][1] = (ushort)(rowb + y0 * 16 + x1);
    sIr[t][2] = (ushort)(rowb + y1 * 16 + x0);
    sIr[t][3] = (ushort)(rowb + y1 * 16 + x1);
    sW4[t][0] = (1.f - wx) * (1.f - wy);
    sW4[t][1] = wx * (1.f - wy);
    sW4[t][2] = (1.f - wx) * wy;
    sW4[t][3] = wx * wy;
  }

  // phase B: qh = [tri | pe] @ Wqb^T + qcb via MFMA, K=320 in 5 chunks of 64
  f32x4 acc[2][2];
#pragma unroll
  for (int m = 0; m < 2; m++)
#pragma unroll
    for (int f = 0; f < 2; f++) acc[m][f] = (f32x4){0.f, 0.f, 0.f, 0.f};

  for (int ct = 0; ct < 5; ct++) {
    __syncthreads();
    {   // stage A chunk: 32 rows x 64 cols
      int r = t >> 3, g = t & 7;
      if (ct < 3) {
        int n = n0 + r;
        int x = n >> 10, y = (n >> 5) & 31, z = n & 31;
        int cell = (ct == 0) ? (z * 32 + x) : (ct == 1) ? (y * 32 + x) : (z * 32 + y);
        const int4 src = *reinterpret_cast<const int4*>(
            tri_tb + ((size_t)(b * 3 + ct) * 1024 + cell) * 64 + g * 8);
        *reinterpret_cast<int4*>(&A_lds[(r * 8 + (g ^ (r & 7))) * 8]) = src;
      } else {
        // pe columns: i = (ct-3)*32 + g*4 .. +3 ; z == r (block 32-aligned)
        int i0 = (ct - 3) * 32 + g * 4;
        bf16x8v v;
#pragma unroll
        for (int q = 0; q < 4; q++) {
          int i = i0 + q;
          float2 exy = cmul(tabX[xq * 64 + i], tabY[yq * 64 + i]);
          float2 e = cmul(exy, tabZ[r * 64 + i]);
          v[q * 2]     = f2b(e.y);   // sin
          v[q * 2 + 1] = f2b(e.x);   // cos
        }
        *reinterpret_cast<bf16x8v*>(&A_lds[(r * 8 + (g ^ (r & 7))) * 8]) = v;
      }
    }
    {   // stage B chunk: 128 cols x 64 k
#pragma unroll
      for (int it = 0; it < 4; it++) {
        int u = it * 256 + t;
        int col = u >> 3, g = u & 7;
        const int4 src = *reinterpret_cast<const int4*>(
            Wqb_s + (size_t)col * 320 + ct * 64 + g * 8);
        *reinterpret_cast<int4*>(&B_lds[(col * 8 + (g ^ (col & 7))) * 8]) = src;
      }
    }
    __syncthreads();
#pragma unroll
    for (int ks = 0; ks < 2; ks++) {
      int kb = ks * 4 + (lane >> 4);
      bf16x8v a[2], bb[2];
#pragma unroll
      for (int m = 0; m < 2; m++) {
        int row = m * 16 + (lane & 15);
        a[m] = *reinterpret_cast<const bf16x8v*>(&A_lds[(row * 8 + (kb ^ (row & 7))) * 8]);
      }
#pragma unroll
      for (int f = 0; f < 2; f++) {
        int col = w * 32 + f * 16 + (lane & 15);
        bb[f] = *reinterpret_cast<const bf16x8v*>(&B_lds[(col * 8 + (kb ^ (col & 7))) * 8]);
      }
#pragma unroll
      for (int m = 0; m < 2; m++)
#pragma unroll
        for (int f = 0; f < 2; f++)
          acc[m][f] = __builtin_amdgcn_mfma_f32_16x16x32_bf16(a[m], bb[f], acc[m][f], 0, 0, 0);
    }
  }
  // epilogue: qh_lds = acc + qcb
#pragma unroll
  for (int m = 0; m < 2; m++)
#pragma unroll
    for (int f = 0; f < 2; f++)
#pragma unroll
      for (int reg = 0; reg < 4; reg++) {
        int row = m * 16 + (lane >> 4) * 4 + reg;
        int col = w * 32 + f * 16 + (lane & 15);
        qh_lds[row * 128 + col] = f2b(acc[m][f][reg] + qcb[col]);
      }
  __syncthreads();

  // phase D: logits
  {
    const int c = t & 127;
    const int h = c >> 4;
    const int sub = t >> 7;
#pragma unroll 2
    for (int it = 0; it < 80; it++) {
      int rj = it * 2 + sub;
      int r = rj / J5;
      ushort4 I4 = *reinterpret_cast<const ushort4*>(sIr[rj]);
      float4 W4 = *reinterpret_cast<const float4*>(sW4[rj]);
      float kh = W4.x * b2f(k2b[(size_t)I4.x * 128 + c])
               + W4.y * b2f(k2b[(size_t)I4.y * 128 + c])
               + W4.z * b2f(k2b[(size_t)I4.z * 128 + c])
               + W4.w * b2f(k2b[(size_t)I4.w * 128 + c]);
      float pv = b2f(qh_lds[r * 128 + c]) * kh;
      pv += __shfl_xor(pv, 1, 16);
      pv += __shfl_xor(pv, 2, 16);
      pv += __shfl_xor(pv, 4, 16);
      pv += __shfl_xor(pv, 8, 16);
      if ((c & 15) == 0) lg[rj * 8 + h] = pv * 0.25f;
    }
  }
  __syncthreads();

  // phase E: softmax over j per (r,h): 32*8 = 256 threads
  {
    int r = t >> 3, h = t & 7;
    float l[J5];
    float m = -1e30f;
#pragma unroll
    for (int j = 0; j < J5; j++) { l[j] = lg[(r * J5 + j) * 8 + h]; m = fmaxf(m, l[j]); }
    float sden = 0.f;
#pragma unroll
    for (int j = 0; j < J5; j++) { l[j] = expf(l[j] - m); sden += l[j]; }
    float inv = 1.0f / sden;
#pragma unroll
    for (int j = 0; j < J5; j++) lg[(r * J5 + j) * 8 + h] = l[j] * inv;
  }
  __syncthreads();

  // phase F: output
  {
    const int c = t & 127;
    const int h = c >> 4;
    const int sub = t >> 7;
#pragma unroll 2
    for (int it = 0; it < 16; it++) {
      int r = it * 2 + sub;
      float o = 0.f;
#pragma unroll
      for (int j = 0; j < J5; j++) {
        int rj = r * J5 + j;
        ushort4 I4 = *reinterpret_cast<const ushort4*>(sIr[rj]);
        float4 W4 = *reinterpret_cast<const float4*>(sW4[rj]);
        float vh = W4.x * b2f(v2b[(size_t)I4.x * 128 + c])
                 + W4.y * b2f(v2b[(size_t)I4.y * 128 + c])
                 + W4.z * b2f(v2b[(size_t)I4.z * 128 + c])
                 + W4.w * b2f(v2b[(size_t)I4.w * 128 + c]);
        o = fmaf(lg[rj * 8 + h], vh, o);
      }
      obuf[((size_t)b * SLABV + nl0 + r) * 128 + c] = __float2bfloat16(o);
    }
  }
}

// ---------- per-slab plane reductions ----------
__global__ __launch_bounds__(128) void k_reduce(const bf16* __restrict__ obuf,
                                                float* __restrict__ pacc, int s) {
  int idx = blockIdx.x;
  int b = blockIdx.y;
  int c = threadIdx.x;
  const bf16* ob = obuf + (size_t)b * SLABV * 128;
  if (idx < 256) {
    int z = idx >> 3, xl = idx & 7;
    float sum = 0.f;
    for (int y = 0; y < 32; y++)
      sum += __bfloat162float(ob[(size_t)(xl * 1024 + y * 32 + z) * 128 + c]);
    pacc[((size_t)(b * 96 + z) * 32 + s * SLABX + xl) * 128 + c] = sum;
  } else if (idx < 512) {
    int e = idx - 256;
    int y = e >> 3, xl = e & 7;
    float sum = 0.f;
    for (int z = 0; z < 32; z++)
      sum += __bfloat162float(ob[(size_t)(xl * 1024 + y * 32 + z) * 128 + c]);
    pacc[((size_t)(b * 96 + 32 + y) * 32 + s * SLABX + xl) * 128 + c] = sum;
  } else {
    int e = idx - 512;
    int z = e >> 5, y = e & 31;
    float sum = 0.f;
    for (int xl = 0; xl < SLABX; xl++)
      sum += __bfloat162float(ob[(size_t)(xl * 1024 + y * 32 + z) * 128 + c]);
    size_t pi = ((size_t)(b * 96 + 64 + z) * 32 + y) * 128 + c;
    pacc[pi] = (s == 0) ? sum : (pacc[pi] + sum);
  }
}

// ---------- final projection ----------
__global__ __launch_bounds__(128) void k_final(
    const float* __restrict__ pacc, const float* __restrict__ Wo,
    const float* __restrict__ obb, float* __restrict__ outp) {
  int bp = blockIdx.x;
  int b = bp / 96, prow = bp % 96;
  int obase = blockIdx.y * 16;
  __shared__ __align__(16) float lds[32 * 129];
  for (int idx = threadIdx.x; idx < 4096; idx += 128) {
    int col = idx >> 7, k = idx & 127;
    lds[col * 129 + k] = pacc[(size_t)bp * 32 * 128 + idx] * (1.0f / 32.0f);
  }
  __syncthreads();
  for (int e = threadIdx.x; e < 16 * 32; e += 128) {
    int o = obase + (e >> 5), col = e & 31;
    float val = obb[o];
    const float* wr = Wo + (size_t)o * 128;
    const float* lr = lds + col * 129;
    for (int k = 0; k < 128; k++) val = fmaf(wr[k], lr[k], val);
    outp[((size_t)(b * 64 + o) * 96 + prow) * 32 + col] = val;
  }
}

extern "C" void kernel_launch(void* const* d_in, const int* in_sizes, int n_in,
                              void* d_out, int out_size, void* d_ws, size_t ws_size,
                              hipStream_t stream) {
  const float* tp     = (const float*)d_in[0];
  const float* img    = (const float*)d_in[1];
  const float* proj   = (const float*)d_in[2];
  const float* k_w    = (const float*)d_in[4];
  const float* k_b    = (const float*)d_in[5];
  const float* q_w    = (const float*)d_in[6];
  const float* q_b    = (const float*)d_in[7];
  const float* v_w    = (const float*)d_in[8];
  const float* v_b    = (const float*)d_in[9];
  const float* in_w   = (const float*)d_in[10];
  const float* in_b   = (const float*)d_in[11];
  const float* out_w  = (const float*)d_in[12];
  const float* out_b  = (const float*)d_in[13];
  const float* proj_w = (const float*)d_in[14];
  const float* proj_b = (const float*)d_in[15];
  const int B = 2;

  float* ws = (float*)d_ws;
  size_t off = 0;
  short*  tri_tb = (short*)(ws + off);  off += 196608;   // 2*3*1024*64 bf16
  short*  Wkvb_s = (short*)(ws + off);  off += 163840;   // 256*1280 bf16
  short*  Wqb_s  = (short*)(ws + off);  off += 20480;    // 128*320 bf16
  float*  in_wT  = ws + off;            off += 32768;    // 128*256
  float*  pe_img = ws + off;            off += 32768;    // 256*128
  float*  peb    = ws + off;            off += 65536;    // 2*256*128
  float2* tabs   = (float2*)(ws + off); off += 12288;    // 3*32*64 cplx
  float*  qcb    = ws + off;            off += 128;
  float*  Wo     = ws + off;            off += 8192;
  float*  obb    = ws + off;            off += 64;
  short*  k2b    = (short*)(ws + off);  off += 163840;   // 2560*128 bf16
  short*  v2b    = (short*)(ws + off);  off += 163840;
  float*  pacc   = ws + off;            off += 786432;   // 2*96*32*128
  float*  zone   = ws + off;            off += 1638400;  // max(imgb, obuf)
  short*  imgb   = (short*)zone;                         // 2560*1280 bf16 (early)
  bf16*   obuf   = (bf16*)zone;                          // 2*8192*128 bf16 (late)
  if (ws_size < off * sizeof(float)) return;  // 13,140,736 B needed

  k_prep_small<<<dim3(344), dim3(256), 0, stream>>>(in_w, tabs, pe_img, in_wT, Wqb_s);
  k_cvt_img<<<dim3(1600), dim3(256), 0, stream>>>(img, imgb);
  int totalT = B * 3 * 1024 * 64;
  k_tri_tb<<<dim3((totalT + 255) / 256), dim3(256), 0, stream>>>(tp, tri_tb, totalT);
  k_fold_w<<<dim3(5, 256), dim3(256), 0, stream>>>(in_w, k_w, v_w, Wkvb_s);
  k_fold_misc<<<dim3(705), dim3(192), 0, stream>>>(
      in_w, in_b, q_w, q_b, k_b, v_b, proj_w, out_w, out_b, proj_b,
      pe_img, in_wT, Wqb_s, peb, Wo, qcb, obb);
  k_gemm_kv<<<dim3(40, 4), dim3(256), 0, stream>>>(imgb, Wkvb_s, peb, k2b, v2b);
  for (int s = 0; s < NSLAB; s++) {
    k_main<<<dim3(SLABV / 32, B), dim3(256), 0, stream>>>(
        tri_tb, Wqb_s, qcb, tabs, k2b, v2b, proj, obuf, s);
    k_reduce<<<dim3(1536, B), dim3(128), 0, stream>>>(obuf, pacc, s);
  }
  k_final<<<dim3(B * 96, 4), dim3(128), 0, stream>>>(pacc, Wo, obb, (float*)d_out);
}

// Round 4
// 164.103 us; speedup vs baseline: 3.0455x; 1.5651x over previous
//
#include <hip/hip_runtime.h>
#include <hip/hip_bf16.h>
#include <cstddef>

#define NVOX 32768
#define J5 5
#define NSLAB 4
#define SLABX 8
#define SLABV 8192
typedef __hip_bfloat16 bf16;
typedef __attribute__((ext_vector_type(8))) short bf16x8v;
typedef __attribute__((ext_vector_type(4))) float f32x4;

static __device__ __forceinline__ float pe_val(int pos, int c) {
  float dv = expf((float)(c & ~1) * (-0.0719557841560639f));
  float arg = (float)pos * dv;
  return (c & 1) ? cosf(arg) : sinf(arg);
}
static __device__ __forceinline__ short f2b(float f) {
  __hip_bfloat16 h = __float2bfloat16(f);
  return *reinterpret_cast<short*>(&h);
}
static __device__ __forceinline__ float b2f(short s) {
  __hip_bfloat16 h = *reinterpret_cast<__hip_bfloat16*>(&s);
  return __bfloat162float(h);
}
static __device__ __forceinline__ float2 cmul(float2 a, float2 b) {
  return make_float2(a.x * b.x - a.y * b.y, a.x * b.y + a.y * b.x);
}

// ---------- prep_small: complex tables, pe_img, in_wT, Wqb pe-part ----------
__global__ __launch_bounds__(256) void k_prep_small(
    const float* __restrict__ in_w, float2* __restrict__ tabs,
    float* __restrict__ pe_img, float* __restrict__ in_wT, short* __restrict__ Wqb_s) {
  int idx = blockIdx.x * 256 + threadIdx.x;
  if (idx < 6144) {                       // tabs: 3 tables x 32 pos x 64 i
    int tb = idx >> 11, rem = idx & 2047;
    int pos = rem >> 6, i = rem & 63;
    float dv = expf((float)(2 * i) * (-0.0719557841560639f));
    float mult = (tb == 0) ? 1024.0f : (tb == 1) ? 32.0f : 1.0f;
    float ang = (float)pos * mult * dv;
    tabs[idx] = make_float2(cosf(ang), sinf(ang));
  } else if (idx < 6144 + 32768) {        // pe_img[256][128]
    int e = idx - 6144;
    int p = e >> 7, c = e & 127;
    pe_img[e] = pe_val(p, c);
  } else if (idx < 6144 + 65536) {        // in_wT[j][256] = in_w[128+cc][j]
    int e = idx - (6144 + 32768);
    int j = e >> 8, cc = e & 255;
    in_wT[e] = in_w[(size_t)(128 + cc) * 128 + j];
  } else if (idx < 6144 + 65536 + 16384) { // Wqb pe-part: Wqb[c][192+j] = Wq[c][j]
    int e = idx - (6144 + 65536);
    int c = e >> 7, j = e & 127;
    Wqb_s[(size_t)c * 320 + 192 + j] = f2b(in_w[(size_t)c * 128 + j]);
  }
}

// ---------- img -> bf16 (skip cls token) ----------
__global__ __launch_bounds__(256) void k_cvt_img(const float* __restrict__ img,
                                                 short* __restrict__ imgb) {
  int e8 = blockIdx.x * 256 + threadIdx.x;   // 2560*160 units of 8
  int row = e8 / 160, k8 = e8 % 160;
  int bj = row >> 8, p = row & 255;
  const float* src = img + ((size_t)(bj * 257 + 1 + p)) * 1280 + k8 * 8;
  float4 a = *(const float4*)src;
  float4 b = *(const float4*)(src + 4);
  bf16x8v v;
  v[0] = f2b(a.x); v[1] = f2b(a.y); v[2] = f2b(a.z); v[3] = f2b(a.w);
  v[4] = f2b(b.x); v[5] = f2b(b.y); v[6] = f2b(b.z); v[7] = f2b(b.w);
  *reinterpret_cast<bf16x8v*>(imgb + (size_t)row * 1280 + k8 * 8) = v;
}

// ---------- triplane transpose -> bf16 channel-contiguous ----------
__global__ __launch_bounds__(256) void k_tri_tb(const float* __restrict__ tp,
                                                short* __restrict__ tt, int total) {
  int idx = blockIdx.x * 256 + threadIdx.x;
  if (idx >= total) return;
  int cc   = idx & 63;
  int rem  = idx >> 6;
  int cell = rem & 1023;
  int segb = rem >> 10;
  int seg = segb % 3, b = segb / 3;
  int i = cell >> 5, j = cell & 31;
  tt[idx] = f2b(tp[(((size_t)(b * 64 + cc)) * 96 + seg * 32 + i) * 32 + j]);
}

// ---------- Wkvb[c][k] = sum_j in_w[128+c][j] * {k_w,v_w}[j][k], bf16 ----------
__global__ __launch_bounds__(256) void k_fold_w(
    const float* __restrict__ in_w, const float* __restrict__ kw,
    const float* __restrict__ vw, short* __restrict__ Wkvb_s) {
  int k = blockIdx.x * 256 + threadIdx.x;   // <1280
  int c = blockIdx.y;                        // <256
  const float* w = (c < 128) ? kw : vw;
  const float* ir = in_w + (size_t)(128 + c) * 128;
  float acc = 0.f;
  for (int j = 0; j < 128; j++) acc = fmaf(ir[j], w[(size_t)j * 1280 + k], acc);
  Wkvb_s[(size_t)c * 1280 + k] = f2b(acc);
}

// ---------- misc folds: Wqc part of Wqb, peb, Wo, qcb/obb ----------
__global__ __launch_bounds__(192) void k_fold_misc(
    const float* __restrict__ in_w, const float* __restrict__ in_b,
    const float* __restrict__ q_w, const float* __restrict__ q_b,
    const float* __restrict__ k_b, const float* __restrict__ v_b,
    const float* __restrict__ proj_w, const float* __restrict__ out_w,
    const float* __restrict__ out_b, const float* __restrict__ proj_b,
    const float* __restrict__ pe_img, const float* __restrict__ in_wT,
    short* __restrict__ Wqb_s, float* __restrict__ peb,
    float* __restrict__ Wo, float* __restrict__ qcb, float* __restrict__ obb) {
  int bx = blockIdx.x, t = threadIdx.x;
  if (bx < 128) {                       // Wqc: Wqb[c][k] k<192
    int c = bx, k = t;
    const float* ir = in_w + (size_t)c * 128;
    float acc = 0.f;
    for (int j = 0; j < 128; j++) acc = fmaf(ir[j], q_w[(size_t)j * 192 + k], acc);
    Wqb_s[(size_t)c * 320 + k] = f2b(acc);
  } else if (bx < 128 + 512) {          // peb[which][p][c]
    if (t >= 128) return;
    int e = bx - 128;
    int which = e >> 8, p = e & 255, c = t;
    const float* bias = which ? v_b : k_b;
    float acc = in_b[128 + which * 128 + c];
    for (int j = 0; j < 128; j++)
      acc = fmaf(bias[j] + pe_img[(size_t)p * 128 + j], in_wT[(size_t)j * 256 + which * 128 + c], acc);
    peb[((size_t)(which * 256 + p)) * 128 + c] = acc;
  } else if (bx < 128 + 512 + 64) {     // Wo[o][c]
    if (t >= 128) return;
    int o = bx - 640, c = t;
    const float* pr = proj_w + (size_t)o * 128;
    float acc = 0.f;
    for (int j = 0; j < 128; j++) acc = fmaf(pr[j], out_w[(size_t)j * 128 + c], acc);
    Wo[(size_t)o * 128 + c] = acc;
  } else {                              // qcb / obb
    if (t < 128) {
      float acc = in_b[t];
      const float* ir = in_w + (size_t)t * 128;
      for (int j = 0; j < 128; j++) acc = fmaf(ir[j], q_b[j], acc);
      qcb[t] = acc;
    }
    if (t < 64) {
      float acc = proj_b[t];
      const float* pr = proj_w + (size_t)t * 128;
      for (int j = 0; j < 128; j++) acc = fmaf(pr[j], out_b[j], acc);
      obb[t] = acc;
    }
  }
}

// ---------- MFMA GEMM: k2v2[2560][256] = imgb @ Wkvb^T + peb ----------
__global__ __launch_bounds__(256) void k_gemm_kv(
    const short* __restrict__ imgb, const short* __restrict__ Wkvb_s,
    const float* __restrict__ peb, short* __restrict__ k2b, short* __restrict__ v2b) {
  __shared__ __align__(16) short A_lds[64 * 64];
  __shared__ __align__(16) short B_lds[64 * 64];
  const int m0 = blockIdx.x * 64;
  const int nb0 = blockIdx.y * 64;
  const int t = threadIdx.x;
  const int lane = t & 63, w = t >> 6;
  f32x4 acc[4];
#pragma unroll
  for (int f = 0; f < 4; f++) acc[f] = (f32x4){0.f, 0.f, 0.f, 0.f};

  for (int ct = 0; ct < 20; ct++) {
    __syncthreads();
#pragma unroll
    for (int it = 0; it < 2; it++) {
      int u = it * 256 + t;
      int r = u >> 3, g = u & 7;
      {
        const int4 src = *reinterpret_cast<const int4*>(imgb + (size_t)(m0 + r) * 1280 + ct * 64 + g * 8);
        *reinterpret_cast<int4*>(&A_lds[(r * 8 + (g ^ (r & 7))) * 8]) = src;
      }
      {
        const int4 src = *reinterpret_cast<const int4*>(Wkvb_s + (size_t)(nb0 + r) * 1280 + ct * 64 + g * 8);
        *reinterpret_cast<int4*>(&B_lds[(r * 8 + (g ^ (r & 7))) * 8]) = src;
      }
    }
    __syncthreads();
#pragma unroll
    for (int ks = 0; ks < 2; ks++) {
      int arow = w * 16 + (lane & 15);
      int akb = ks * 4 + (lane >> 4);
      bf16x8v a = *reinterpret_cast<const bf16x8v*>(&A_lds[(arow * 8 + (akb ^ (arow & 7))) * 8]);
#pragma unroll
      for (int f = 0; f < 4; f++) {
        int bcol = f * 16 + (lane & 15);
        bf16x8v bb = *reinterpret_cast<const bf16x8v*>(&B_lds[(bcol * 8 + (akb ^ (bcol & 7))) * 8]);
        acc[f] = __builtin_amdgcn_mfma_f32_16x16x32_bf16(a, bb, acc[f], 0, 0, 0);
      }
    }
  }
#pragma unroll
  for (int f = 0; f < 4; f++) {
#pragma unroll
    for (int reg = 0; reg < 4; reg++) {
      int grow = m0 + w * 16 + (lane >> 4) * 4 + reg;
      int gcol = nb0 + f * 16 + (lane & 15);
      int p = grow & 255;
      int which = gcol >> 7, c = gcol & 127;
      float val = acc[f][reg] + peb[((size_t)(which * 256 + p)) * 128 + c];
      short* dst = which ? v2b : k2b;
      dst[(size_t)grow * 128 + c] = f2b(val);
    }
  }
}

// ---------- fused main (16 vox/block): MFMA q-GEMM + proj + sample + attention ----------
__global__ __launch_bounds__(256) void k_main(
    const short* __restrict__ tri_tb, const short* __restrict__ Wqb_s,
    const float* __restrict__ qcb, const float2* __restrict__ tabs,
    const short* __restrict__ k2b, const short* __restrict__ v2b,
    const float* __restrict__ proj, bf16* __restrict__ obuf, int s) {
  __shared__ __align__(16) short A_lds[16 * 64];
  __shared__ __align__(16) short B_lds[128 * 64];
  __shared__ __align__(16) short qh_lds[16 * 128];
  __shared__ __align__(16) ushort sIr[80][4];
  __shared__ __align__(16) float sW4[80][4];
  __shared__ __align__(16) float lg[80 * 8];
  const int b = blockIdx.y;
  const int nl0 = blockIdx.x * 16;
  const int n0 = s * SLABV + nl0;
  const int t = threadIdx.x;
  const int lane = t & 63, w = t >> 6;
  const int xq = n0 >> 10, yq = (n0 >> 5) & 31, zq0 = n0 & 31;  // uniform; zq0 in {0,16}
  const float2* tabX = tabs;
  const float2* tabY = tabs + 2048;
  const float2* tabZ = tabs + 4096;

  // phase C: projection + bilinear taps (t < 80)
  if (t < 80) {
    int r = t / J5, j = t % J5;
    int n = n0 + r;
    int x = n >> 10, y = (n >> 5) & 31, z = n & 31;
    const float SC = (float)(1.0 + 0.1 + 1e-05);
    float fx = ((float)x / 31.0f - 0.5f) * 2.0f * SC;
    float fy = ((float)y / 31.0f - 0.5f) * 2.0f * SC;
    float fz = ((float)z / 31.0f - 0.5f) * 2.0f * SC;
    const float* P = proj + (size_t)(b * J5 + j) * 16;
    float pc0 = fmaf(fx, P[0], fmaf(fy, P[1], fmaf(fz, P[2],  P[3])));
    float pc1 = fmaf(fx, P[4], fmaf(fy, P[5], fmaf(fz, P[6],  P[7])));
    float pc2 = fmaf(fx, P[8], fmaf(fy, P[9], fmaf(fz, P[10], P[11])));
    float px = pc0 / pc2, py = pc1 / pc2;
    float gx = fminf(fmaxf((px / 223.0f - 0.5f) * 2.0f, -1.0f), 1.0f);
    float gy = fminf(fmaxf((py / 223.0f - 0.5f) * 2.0f, -1.0f), 1.0f);
    float ux = (gx + 1.0f) * 0.5f * 15.0f;
    float uy = (gy + 1.0f) * 0.5f * 15.0f;
    float fx0 = floorf(ux), fy0 = floorf(uy);
    int x0 = (int)fx0, y0 = (int)fy0;
    float wx = ux - fx0, wy = uy - fy0;
    int x1 = min(x0 + 1, 15), y1 = min(y0 + 1, 15);
    x0 = min(max(x0, 0), 15); y0 = min(max(y0, 0), 15);
    int rowb = (b * J5 + j) * 256;
    sIr[t][0] = (ushort)(rowb + y0 * 16 + x0);
    sIr[t][1] = (ushort)(rowb + y0 * 16 + x1);
    sIr[t][2] = (ushort)(rowb + y1 * 16 + x0);
    sIr[t][3] = (ushort)(rowb + y1 * 16 + x1);
    sW4[t][0] = (1.f - wx) * (1.f - wy);
    sW4[t][1] = wx * (1.f - wy);
    sW4[t][2] = (1.f - wx) * wy;
    sW4[t][3] = wx * wy;
  }

  // phase B: qh = [tri | pe] @ Wqb^T + qcb via MFMA, K=320 in 5 chunks of 64
  f32x4 acc[2];
  acc[0] = (f32x4){0.f, 0.f, 0.f, 0.f};
  acc[1] = (f32x4){0.f, 0.f, 0.f, 0.f};

  for (int ct = 0; ct < 5; ct++) {
    __syncthreads();
    if (t < 128) {   // stage A chunk: 16 rows x 64 cols
      int r = t >> 3, g = t & 7;
      if (ct < 3) {
        int n = n0 + r;
        int x = n >> 10, y = (n >> 5) & 31, z = n & 31;
        int cell = (ct == 0) ? (z * 32 + x) : (ct == 1) ? (y * 32 + x) : (z * 32 + y);
        const int4 src = *reinterpret_cast<const int4*>(
            tri_tb + ((size_t)(b * 3 + ct) * 1024 + cell) * 64 + g * 8);
        *reinterpret_cast<int4*>(&A_lds[(r * 8 + (g ^ (r & 7))) * 8]) = src;
      } else {
        int i0 = (ct - 3) * 32 + g * 4;
        int z = zq0 + r;
        bf16x8v v;
#pragma unroll
        for (int q = 0; q < 4; q++) {
          int i = i0 + q;
          float2 exy = cmul(tabX[xq * 64 + i], tabY[yq * 64 + i]);
          float2 e = cmul(exy, tabZ[z * 64 + i]);
          v[q * 2]     = f2b(e.y);   // sin
          v[q * 2 + 1] = f2b(e.x);   // cos
        }
        *reinterpret_cast<bf16x8v*>(&A_lds[(r * 8 + (g ^ (r & 7))) * 8]) = v;
      }
    }
    {   // stage B chunk: 128 cols x 64 k
#pragma unroll
      for (int it = 0; it < 4; it++) {
        int u = it * 256 + t;
        int col = u >> 3, g = u & 7;
        const int4 src = *reinterpret_cast<const int4*>(
            Wqb_s + (size_t)col * 320 + ct * 64 + g * 8);
        *reinterpret_cast<int4*>(&B_lds[(col * 8 + (g ^ (col & 7))) * 8]) = src;
      }
    }
    __syncthreads();
#pragma unroll
    for (int ks = 0; ks < 2; ks++) {
      int kb = ks * 4 + (lane >> 4);
      int arow = lane & 15;
      bf16x8v a = *reinterpret_cast<const bf16x8v*>(&A_lds[(arow * 8 + (kb ^ (arow & 7))) * 8]);
#pragma unroll
      for (int f = 0; f < 2; f++) {
        int col = w * 32 + f * 16 + (lane & 15);
        bf16x8v bb = *reinterpret_cast<const bf16x8v*>(&B_lds[(col * 8 + (kb ^ (col & 7))) * 8]);
        acc[f] = __builtin_amdgcn_mfma_f32_16x16x32_bf16(a, bb, acc[f], 0, 0, 0);
      }
    }
  }
  // epilogue: qh_lds = acc + qcb (bf16)
#pragma unroll
  for (int f = 0; f < 2; f++)
#pragma unroll
    for (int reg = 0; reg < 4; reg++) {
      int row = (lane >> 4) * 4 + reg;
      int col = w * 32 + f * 16 + (lane & 15);
      qh_lds[row * 128 + col] = f2b(acc[f][reg] + qcb[col]);
    }
  __syncthreads();

  // phase D: logits — octet-per-thread, bf16x8 loads, single shfl
  {
    const int oct = t & 15, rjIdx = t >> 4;
    const int c0 = oct * 8;
#pragma unroll
    for (int it = 0; it < 5; it++) {
      int rj = rjIdx + it * 16;
      int r = rj / J5;
      ushort4 I4 = *reinterpret_cast<const ushort4*>(sIr[rj]);
      float4 W4 = *reinterpret_cast<const float4*>(sW4[rj]);
      bf16x8v t0 = *reinterpret_cast<const bf16x8v*>(k2b + (size_t)I4.x * 128 + c0);
      bf16x8v t1 = *reinterpret_cast<const bf16x8v*>(k2b + (size_t)I4.y * 128 + c0);
      bf16x8v t2 = *reinterpret_cast<const bf16x8v*>(k2b + (size_t)I4.z * 128 + c0);
      bf16x8v t3 = *reinterpret_cast<const bf16x8v*>(k2b + (size_t)I4.w * 128 + c0);
      bf16x8v q8 = *reinterpret_cast<const bf16x8v*>(&qh_lds[r * 128 + c0]);
      float pv = 0.f;
#pragma unroll
      for (int e = 0; e < 8; e++) {
        float kh = fmaf(W4.x, b2f(t0[e]), fmaf(W4.y, b2f(t1[e]),
                   fmaf(W4.z, b2f(t2[e]), W4.w * b2f(t3[e]))));
        pv = fmaf(b2f(q8[e]), kh, pv);
      }
      pv += __shfl_xor(pv, 1);
      if (!(oct & 1)) lg[rj * 8 + (oct >> 1)] = pv * 0.25f;
    }
  }
  __syncthreads();

  // phase E: softmax over j per (r,h): 16*8 = 128 threads
  if (t < 128) {
    int r = t >> 3, h = t & 7;
    float l[J5];
    float m = -1e30f;
#pragma unroll
    for (int j = 0; j < J5; j++) { l[j] = lg[(r * J5 + j) * 8 + h]; m = fmaxf(m, l[j]); }
    float sden = 0.f;
#pragma unroll
    for (int j = 0; j < J5; j++) { l[j] = expf(l[j] - m); sden += l[j]; }
    float inv = 1.0f / sden;
#pragma unroll
    for (int j = 0; j < J5; j++) lg[(r * J5 + j) * 8 + h] = l[j] * inv;
  }
  __syncthreads();

  // phase F: output — octet-per-thread accumulation
  {
    const int oct = t & 15, r = t >> 4;
    const int c0 = oct * 8;
    float o8[8] = {0.f, 0.f, 0.f, 0.f, 0.f, 0.f, 0.f, 0.f};
#pragma unroll
    for (int j = 0; j < J5; j++) {
      int rj = r * J5 + j;
      float aw = lg[rj * 8 + (oct >> 1)];
      ushort4 I4 = *reinterpret_cast<const ushort4*>(sIr[rj]);
      float4 W4 = *reinterpret_cast<const float4*>(sW4[rj]);
      float w0 = aw * W4.x, w1 = aw * W4.y, w2 = aw * W4.z, w3 = aw * W4.w;
      bf16x8v t0 = *reinterpret_cast<const bf16x8v*>(v2b + (size_t)I4.x * 128 + c0);
      bf16x8v t1 = *reinterpret_cast<const bf16x8v*>(v2b + (size_t)I4.y * 128 + c0);
      bf16x8v t2 = *reinterpret_cast<const bf16x8v*>(v2b + (size_t)I4.z * 128 + c0);
      bf16x8v t3 = *reinterpret_cast<const bf16x8v*>(v2b + (size_t)I4.w * 128 + c0);
#pragma unroll
      for (int e = 0; e < 8; e++) {
        o8[e] = fmaf(w0, b2f(t0[e]), o8[e]);
        o8[e] = fmaf(w1, b2f(t1[e]), o8[e]);
        o8[e] = fmaf(w2, b2f(t2[e]), o8[e]);
        o8[e] = fmaf(w3, b2f(t3[e]), o8[e]);
      }
    }
    bf16x8v out;
#pragma unroll
    for (int e = 0; e < 8; e++) out[e] = f2b(o8[e]);
    *reinterpret_cast<bf16x8v*>((short*)obuf + ((size_t)b * SLABV + nl0 + r) * 128 + c0) = out;
  }
}

// ---------- per-slab plane reductions (vectorized: 4 rows/block, ushort4 loads) ----------
__global__ __launch_bounds__(128) void k_reduce(const bf16* __restrict__ obuf,
                                                float* __restrict__ pacc, int s) {
  int blk = blockIdx.x;          // 0..383
  int b = blockIdx.y;
  int t = threadIdx.x;
  int quad = t & 31, sub = t >> 5;
  int c0 = quad * 4;
  const ushort* ob = (const ushort*)obuf + (size_t)b * SLABV * 128;
  float4 acc = {0.f, 0.f, 0.f, 0.f};
  if (blk < 64) {                // xz rows: row = z*8+xl ; sum over y
    int row = blk * 4 + sub;
    int z = row >> 3, xl = row & 7;
    for (int y = 0; y < 32; y++) {
      ushort4 u = *(const ushort4*)(ob + ((size_t)(xl * 1024 + y * 32 + z) * 128 + c0));
      acc.x += b2f((short)u.x); acc.y += b2f((short)u.y);
      acc.z += b2f((short)u.z); acc.w += b2f((short)u.w);
    }
    *(float4*)(&pacc[((size_t)(b * 96 + z) * 32 + s * SLABX + xl) * 128 + c0]) = acc;
  } else if (blk < 128) {        // xy rows: row = y*8+xl ; sum over z
    int row = (blk - 64) * 4 + sub;
    int y = row >> 3, xl = row & 7;
    for (int z = 0; z < 32; z++) {
      ushort4 u = *(const ushort4*)(ob + ((size_t)(xl * 1024 + y * 32 + z) * 128 + c0));
      acc.x += b2f((short)u.x); acc.y += b2f((short)u.y);
      acc.z += b2f((short)u.z); acc.w += b2f((short)u.w);
    }
    *(float4*)(&pacc[((size_t)(b * 96 + 32 + y) * 32 + s * SLABX + xl) * 128 + c0]) = acc;
  } else {                       // yz rows: row = z*32+y ; partial over x, accumulate
    int row = (blk - 128) * 4 + sub;
    int z = row >> 5, y = row & 31;
    for (int xl = 0; xl < SLABX; xl++) {
      ushort4 u = *(const ushort4*)(ob + ((size_t)(xl * 1024 + y * 32 + z) * 128 + c0));
      acc.x += b2f((short)u.x); acc.y += b2f((short)u.y);
      acc.z += b2f((short)u.z); acc.w += b2f((short)u.w);
    }
    float* pp = &pacc[((size_t)(b * 96 + 64 + z) * 32 + y) * 128 + c0];
    if (s != 0) {
      float4 prev = *(const float4*)pp;
      acc.x += prev.x; acc.y += prev.y; acc.z += prev.z; acc.w += prev.w;
    }
    *(float4*)pp = acc;
  }
}

// ---------- final projection ----------
__global__ __launch_bounds__(128) void k_final(
    const float* __restrict__ pacc, const float* __restrict__ Wo,
    const float* __restrict__ obb, float* __restrict__ outp) {
  int bp = blockIdx.x;
  int b = bp / 96, prow = bp % 96;
  int obase = blockIdx.y * 16;
  __shared__ __align__(16) float lds[32 * 129];
  for (int idx = threadIdx.x; idx < 4096; idx += 128) {
    int col = idx >> 7, k = idx & 127;
    lds[col * 129 + k] = pacc[(size_t)bp * 32 * 128 + idx] * (1.0f / 32.0f);
  }
  __syncthreads();
  for (int e = threadIdx.x; e < 16 * 32; e += 128) {
    int o = obase + (e >> 5), col = e & 31;
    float val = obb[o];
    const float* wr = Wo + (size_t)o * 128;
    const float* lr = lds + col * 129;
    for (int k = 0; k < 128; k++) val = fmaf(wr[k], lr[k], val);
    outp[((size_t)(b * 64 + o) * 96 + prow) * 32 + col] = val;
  }
}

extern "C" void kernel_launch(void* const* d_in, const int* in_sizes, int n_in,
                              void* d_out, int out_size, void* d_ws, size_t ws_size,
                              hipStream_t stream) {
  const float* tp     = (const float*)d_in[0];
  const float* img    = (const float*)d_in[1];
  const float* proj   = (const float*)d_in[2];
  const float* k_w    = (const float*)d_in[4];
  const float* k_b    = (const float*)d_in[5];
  const float* q_w    = (const float*)d_in[6];
  const float* q_b    = (const float*)d_in[7];
  const float* v_w    = (const float*)d_in[8];
  const float* v_b    = (const float*)d_in[9];
  const float* in_w   = (const float*)d_in[10];
  const float* in_b   = (const float*)d_in[11];
  const float* out_w  = (const float*)d_in[12];
  const float* out_b  = (const float*)d_in[13];
  const float* proj_w = (const float*)d_in[14];
  const float* proj_b = (const float*)d_in[15];
  const int B = 2;

  float* ws = (float*)d_ws;
  size_t off = 0;
  short*  tri_tb = (short*)(ws + off);  off += 196608;   // 2*3*1024*64 bf16
  short*  Wkvb_s = (short*)(ws + off);  off += 163840;   // 256*1280 bf16
  short*  Wqb_s  = (short*)(ws + off);  off += 20480;    // 128*320 bf16
  float*  in_wT  = ws + off;            off += 32768;    // 128*256
  float*  pe_img = ws + off;            off += 32768;    // 256*128
  float*  peb    = ws + off;            off += 65536;    // 2*256*128
  float2* tabs   = (float2*)(ws + off); off += 12288;    // 3*32*64 cplx
  float*  qcb    = ws + off;            off += 128;
  float*  Wo     = ws + off;            off += 8192;
  float*  obb    = ws + off;            off += 64;
  short*  k2b    = (short*)(ws + off);  off += 163840;   // 2560*128 bf16
  short*  v2b    = (short*)(ws + off);  off += 163840;
  float*  pacc   = ws + off;            off += 786432;   // 2*96*32*128
  float*  zone   = ws + off;            off += 1638400;  // max(imgb, obuf)
  short*  imgb   = (short*)zone;                         // 2560*1280 bf16 (early)
  bf16*   obuf   = (bf16*)zone;                          // 2*8192*128 bf16 (late)
  if (ws_size < off * sizeof(float)) return;  // 13,140,736 B needed

  k_prep_small<<<dim3(344), dim3(256), 0, stream>>>(in_w, tabs, pe_img, in_wT, Wqb_s);
  k_cvt_img<<<dim3(1600), dim3(256), 0, stream>>>(img, imgb);
  int totalT = B * 3 * 1024 * 64;
  k_tri_tb<<<dim3((totalT + 255) / 256), dim3(256), 0, stream>>>(tp, tri_tb, totalT);
  k_fold_w<<<dim3(5, 256), dim3(256), 0, stream>>>(in_w, k_w, v_w, Wkvb_s);
  k_fold_misc<<<dim3(705), dim3(192), 0, stream>>>(
      in_w, in_b, q_w, q_b, k_b, v_b, proj_w, out_w, out_b, proj_b,
      pe_img, in_wT, Wqb_s, peb, Wo, qcb, obb);
  k_gemm_kv<<<dim3(40, 4), dim3(256), 0, stream>>>(imgb, Wkvb_s, peb, k2b, v2b);
  for (int s = 0; s < NSLAB; s++) {
    k_main<<<dim3(SLABV / 16, B), dim3(256), 0, stream>>>(
        tri_tb, Wqb_s, qcb, tabs, k2b, v2b, proj, obuf, s);
    k_reduce<<<dim3(384, B), dim3(128), 0, stream>>>(obuf, pacc, s);
  }
  k_final<<<dim3(B * 96, 4), dim3(128), 0, stream>>>(pacc, Wo, obb, (float*)d_out);
}

// Round 5
// 117.464 us; speedup vs baseline: 4.2548x; 1.3971x over previous
//
#include <hip/hip_runtime.h>
#include <hip/hip_bf16.h>
#include <cstddef>

#define NVOX 32768
#define J5 5
typedef __hip_bfloat16 bf16;
typedef __attribute__((ext_vector_type(8))) short bf16x8v;
typedef __attribute__((ext_vector_type(4))) float f32x4;

static __device__ __forceinline__ float pe_val(int pos, int c) {
  float dv = expf((float)(c & ~1) * (-0.0719557841560639f));
  float arg = (float)pos * dv;
  return (c & 1) ? cosf(arg) : sinf(arg);
}
static __device__ __forceinline__ short f2b(float f) {
  __hip_bfloat16 h = __float2bfloat16(f);
  return *reinterpret_cast<short*>(&h);
}
static __device__ __forceinline__ float b2f(short s) {
  __hip_bfloat16 h = *reinterpret_cast<__hip_bfloat16*>(&s);
  return __bfloat162float(h);
}
static __device__ __forceinline__ float2 cmul(float2 a, float2 b) {
  return make_float2(a.x * b.x - a.y * b.y, a.x * b.y + a.y * b.x);
}

// block-range boundaries for k_prep sections
#define NB_TABS   24      // tabs: 6144
#define NB_WQPE   64      // Wqb pe-part: 16384
#define NB_WQC    96      // Wqc: 24576
#define NB_WO     32      // Wo: 8192
#define NB_QCB    1       // qcb+obb
#define NB_CVT    1600    // img cvt: 409600 (units of 8)
#define NB_TRI    1536    // tri transpose: 393216
#define NB_FOLDW  1280    // Wkvb fold: 327680
#define NB_PEB    512     // peb: 512 (which,p) rows
#define B_TABS   0
#define B_WQPE   (B_TABS + NB_TABS)
#define B_WQC    (B_WQPE + NB_WQPE)
#define B_WO     (B_WQC + NB_WQC)
#define B_QCB    (B_WO + NB_WO)
#define B_CVT    (B_QCB + NB_QCB)
#define B_TRI    (B_CVT + NB_CVT)
#define B_FOLDW  (B_TRI + NB_TRI)
#define B_PEB    (B_FOLDW + NB_FOLDW)
#define NB_TOTAL (B_PEB + NB_PEB)   // 5145

// ---------- one merged prep kernel: all independent precomputation ----------
__global__ __launch_bounds__(256) void k_prep(
    const float* __restrict__ img, const float* __restrict__ tp,
    const float* __restrict__ k_w, const float* __restrict__ k_b,
    const float* __restrict__ q_w, const float* __restrict__ q_b,
    const float* __restrict__ v_w, const float* __restrict__ v_b,
    const float* __restrict__ in_w, const float* __restrict__ in_b,
    const float* __restrict__ out_w, const float* __restrict__ out_b,
    const float* __restrict__ proj_w, const float* __restrict__ proj_b,
    float2* __restrict__ tabs, short* __restrict__ Wqb_s, float* __restrict__ Wo,
    float* __restrict__ qcb, float* __restrict__ obb, short* __restrict__ imgb,
    short* __restrict__ tri_tb, short* __restrict__ Wkvb_s, float* __restrict__ peb) {
  __shared__ float s_pe[128];
  const int bx = blockIdx.x, t = threadIdx.x;

  if (bx < B_WQPE) {                    // tabs: 3 tables x 32 pos x 64 i
    int idx = bx * 256 + t;
    if (idx < 6144) {
      int tb = idx >> 11, rem = idx & 2047;
      int pos = rem >> 6, i = rem & 63;
      float dv = expf((float)(2 * i) * (-0.0719557841560639f));
      float mult = (tb == 0) ? 1024.0f : (tb == 1) ? 32.0f : 1.0f;
      float ang = (float)pos * mult * dv;
      tabs[idx] = make_float2(cosf(ang), sinf(ang));
    }
  } else if (bx < B_WQC) {              // Wqb pe-part: Wqb[c][192+j] = Wq[c][j]
    int e = (bx - B_WQPE) * 256 + t;    // < 16384
    int c = e >> 7, j = e & 127;
    Wqb_s[(size_t)c * 320 + 192 + j] = f2b(in_w[(size_t)c * 128 + j]);
  } else if (bx < B_WO) {               // Wqc: Wqb[c][k] = Wq[c,:] . q_w[:,k]
    int e = (bx - B_WQC) * 256 + t;     // < 24576
    int c = e / 192, k = e % 192;
    const float* ir = in_w + (size_t)c * 128;
    float acc = 0.f;
    for (int j = 0; j < 128; j++) acc = fmaf(ir[j], q_w[(size_t)j * 192 + k], acc);
    Wqb_s[(size_t)c * 320 + k] = f2b(acc);
  } else if (bx < B_QCB) {              // Wo[o][c] = proj_w[o,:] . out_w[:,c]
    int e = (bx - B_WO) * 256 + t;      // < 8192
    int o = e >> 7, c = e & 127;
    const float* pr = proj_w + (size_t)o * 128;
    float acc = 0.f;
    for (int j = 0; j < 128; j++) acc = fmaf(pr[j], out_w[(size_t)j * 128 + c], acc);
    Wo[e] = acc;
  } else if (bx < B_CVT) {              // qcb / obb
    if (t < 128) {
      float acc = in_b[t];
      const float* ir = in_w + (size_t)t * 128;
      for (int j = 0; j < 128; j++) acc = fmaf(ir[j], q_b[j], acc);
      qcb[t] = acc;
    }
    if (t < 64) {
      float acc = proj_b[t];
      const float* pr = proj_w + (size_t)t * 128;
      for (int j = 0; j < 128; j++) acc = fmaf(pr[j], out_b[j], acc);
      obb[t] = acc;
    }
  } else if (bx < B_TRI) {              // img -> bf16 (skip cls)
    int e8 = (bx - B_CVT) * 256 + t;    // < 409600
    int row = e8 / 160, k8 = e8 % 160;
    int bj = row >> 8, p = row & 255;
    const float* src = img + ((size_t)(bj * 257 + 1 + p)) * 1280 + k8 * 8;
    float4 a = *(const float4*)src;
    float4 b = *(const float4*)(src + 4);
    bf16x8v v;
    v[0] = f2b(a.x); v[1] = f2b(a.y); v[2] = f2b(a.z); v[3] = f2b(a.w);
    v[4] = f2b(b.x); v[5] = f2b(b.y); v[6] = f2b(b.z); v[7] = f2b(b.w);
    *reinterpret_cast<bf16x8v*>(imgb + (size_t)row * 1280 + k8 * 8) = v;
  } else if (bx < B_FOLDW) {            // triplane transpose -> bf16
    int idx = (bx - B_TRI) * 256 + t;   // < 393216
    int cc   = idx & 63;
    int rem  = idx >> 6;
    int cell = rem & 1023;
    int segb = rem >> 10;
    int seg = segb % 3, b = segb / 3;
    int i = cell >> 5, j = cell & 31;
    tri_tb[idx] = f2b(tp[(((size_t)(b * 64 + cc)) * 96 + seg * 32 + i) * 32 + j]);
  } else if (bx < B_PEB) {              // Wkvb[c][k] = Wk/Wv[c,:] . {k_w,v_w}[:,k]
    int u = (bx - B_FOLDW) * 256 + t;   // < 327680
    int c = u / 1280, k = u % 1280;
    const float* w = (c < 128) ? k_w : v_w;
    const float* ir = in_w + (size_t)(128 + c) * 128;
    float acc = 0.f;
    for (int j = 0; j < 128; j++) acc = fmaf(ir[j], w[(size_t)j * 1280 + k], acc);
    Wkvb_s[(size_t)c * 1280 + k] = f2b(acc);
  } else {                              // peb[which][p][c]
    int e = bx - B_PEB;                 // < 512
    int which = e >> 8, p = e & 255;
    if (t < 128) {
      const float* bias = which ? v_b : k_b;
      s_pe[t] = bias[t] + pe_val(p, t);
    }
    __syncthreads();
    if (t < 128) {
      int c = t;
      const float* wr = in_w + (size_t)(128 + which * 128 + c) * 128;
      float acc = in_b[128 + which * 128 + c];
      for (int j = 0; j < 128; j++) acc = fmaf(s_pe[j], wr[j], acc);
      peb[((size_t)(which * 256 + p)) * 128 + c] = acc;
    }
  }
}

// ---------- MFMA GEMM: k2v2[2560][256] = imgb @ Wkvb^T + peb ----------
__global__ __launch_bounds__(256) void k_gemm_kv(
    const short* __restrict__ imgb, const short* __restrict__ Wkvb_s,
    const float* __restrict__ peb, short* __restrict__ k2b, short* __restrict__ v2b) {
  __shared__ __align__(16) short A_lds[64 * 64];
  __shared__ __align__(16) short B_lds[64 * 64];
  const int m0 = blockIdx.x * 64;
  const int nb0 = blockIdx.y * 64;
  const int t = threadIdx.x;
  const int lane = t & 63, w = t >> 6;
  f32x4 acc[4];
#pragma unroll
  for (int f = 0; f < 4; f++) acc[f] = (f32x4){0.f, 0.f, 0.f, 0.f};

  for (int ct = 0; ct < 20; ct++) {
    __syncthreads();
#pragma unroll
    for (int it = 0; it < 2; it++) {
      int u = it * 256 + t;
      int r = u >> 3, g = u & 7;
      {
        const int4 src = *reinterpret_cast<const int4*>(imgb + (size_t)(m0 + r) * 1280 + ct * 64 + g * 8);
        *reinterpret_cast<int4*>(&A_lds[(r * 8 + (g ^ (r & 7))) * 8]) = src;
      }
      {
        const int4 src = *reinterpret_cast<const int4*>(Wkvb_s + (size_t)(nb0 + r) * 1280 + ct * 64 + g * 8);
        *reinterpret_cast<int4*>(&B_lds[(r * 8 + (g ^ (r & 7))) * 8]) = src;
      }
    }
    __syncthreads();
#pragma unroll
    for (int ks = 0; ks < 2; ks++) {
      int arow = w * 16 + (lane & 15);
      int akb = ks * 4 + (lane >> 4);
      bf16x8v a = *reinterpret_cast<const bf16x8v*>(&A_lds[(arow * 8 + (akb ^ (arow & 7))) * 8]);
#pragma unroll
      for (int f = 0; f < 4; f++) {
        int bcol = f * 16 + (lane & 15);
        bf16x8v bb = *reinterpret_cast<const bf16x8v*>(&B_lds[(bcol * 8 + (akb ^ (bcol & 7))) * 8]);
        acc[f] = __builtin_amdgcn_mfma_f32_16x16x32_bf16(a, bb, acc[f], 0, 0, 0);
      }
    }
  }
#pragma unroll
  for (int f = 0; f < 4; f++) {
#pragma unroll
    for (int reg = 0; reg < 4; reg++) {
      int grow = m0 + w * 16 + (lane >> 4) * 4 + reg;
      int gcol = nb0 + f * 16 + (lane & 15);
      int p = grow & 255;
      int which = gcol >> 7, c = gcol & 127;
      float val = acc[f][reg] + peb[((size_t)(which * 256 + p)) * 128 + c];
      short* dst = which ? v2b : k2b;
      dst[(size_t)grow * 128 + c] = f2b(val);
    }
  }
}

// ---------- fused main (32 vox/block, full volume): MFMA q-GEMM + proj + sample + attention ----------
__global__ __launch_bounds__(256) void k_main(
    const short* __restrict__ tri_tb, const short* __restrict__ Wqb_s,
    const float* __restrict__ qcb, const float2* __restrict__ tabs,
    const short* __restrict__ k2b, const short* __restrict__ v2b,
    const float* __restrict__ proj, bf16* __restrict__ obuf) {
  __shared__ __align__(16) short A_lds[32 * 64];
  __shared__ __align__(16) short B_lds[128 * 64];
  __shared__ __align__(16) short qh_lds[32 * 128];
  __shared__ __align__(16) ushort sIr[160][4];
  __shared__ __align__(16) float sW4[160][4];
  __shared__ __align__(16) float lg[160 * 8];
  const int b = blockIdx.y;
  const int n0 = blockIdx.x * 32;
  const int t = threadIdx.x;
  const int lane = t & 63, w = t >> 6;
  const int xq = n0 >> 10, yq = (n0 >> 5) & 31;   // uniform; z spans 0..31
  const float2* tabX = tabs;
  const float2* tabY = tabs + 2048;
  const float2* tabZ = tabs + 4096;

  // phase C: projection + bilinear taps (t < 160)
  if (t < 160) {
    int r = t / J5, j = t % J5;
    int n = n0 + r;
    int x = n >> 10, y = (n >> 5) & 31, z = n & 31;
    const float SC = (float)(1.0 + 0.1 + 1e-05);
    float fx = ((float)x / 31.0f - 0.5f) * 2.0f * SC;
    float fy = ((float)y / 31.0f - 0.5f) * 2.0f * SC;
    float fz = ((float)z / 31.0f - 0.5f) * 2.0f * SC;
    const float* P = proj + (size_t)(b * J5 + j) * 16;
    float pc0 = fmaf(fx, P[0], fmaf(fy, P[1], fmaf(fz, P[2],  P[3])));
    float pc1 = fmaf(fx, P[4], fmaf(fy, P[5], fmaf(fz, P[6],  P[7])));
    float pc2 = fmaf(fx, P[8], fmaf(fy, P[9], fmaf(fz, P[10], P[11])));
    float px = pc0 / pc2, py = pc1 / pc2;
    float gx = fminf(fmaxf((px / 223.0f - 0.5f) * 2.0f, -1.0f), 1.0f);
    float gy = fminf(fmaxf((py / 223.0f - 0.5f) * 2.0f, -1.0f), 1.0f);
    float ux = (gx + 1.0f) * 0.5f * 15.0f;
    float uy = (gy + 1.0f) * 0.5f * 15.0f;
    float fx0 = floorf(ux), fy0 = floorf(uy);
    int x0 = (int)fx0, y0 = (int)fy0;
    float wx = ux - fx0, wy = uy - fy0;
    int x1 = min(x0 + 1, 15), y1 = min(y0 + 1, 15);
    x0 = min(max(x0, 0), 15); y0 = min(max(y0, 0), 15);
    int rowb = (b * J5 + j) * 256;
    sIr[t][0] = (ushort)(rowb + y0 * 16 + x0);
    sIr[t][1] = (ushort)(rowb + y0 * 16 + x1);
    sIr[t][2] = (ushort)(rowb + y1 * 16 + x0);
    sIr[t][3] = (ushort)(rowb + y1 * 16 + x1);
    sW4[t][0] = (1.f - wx) * (1.f - wy);
    sW4[t][1] = wx * (1.f - wy);
    sW4[t][2] = (1.f - wx) * wy;
    sW4[t][3] = wx * wy;
  }

  // phase B: qh = [tri | pe] @ Wqb^T + qcb via MFMA, K=320 in 5 chunks of 64
  f32x4 acc[2][2];
#pragma unroll
  for (int m = 0; m < 2; m++)
#pragma unroll
    for (int f = 0; f < 2; f++) acc[m][f] = (f32x4){0.f, 0.f, 0.f, 0.f};

  for (int ct = 0; ct < 5; ct++) {
    __syncthreads();
    {   // stage A chunk: 32 rows x 64 cols (256 threads)
      int r = t >> 3, g = t & 7;
      if (ct < 3) {
        int n = n0 + r;
        int x = n >> 10, y = (n >> 5) & 31, z = n & 31;
        int cell = (ct == 0) ? (z * 32 + x) : (ct == 1) ? (y * 32 + x) : (z * 32 + y);
        const int4 src = *reinterpret_cast<const int4*>(
            tri_tb + ((size_t)(b * 3 + ct) * 1024 + cell) * 64 + g * 8);
        *reinterpret_cast<int4*>(&A_lds[(r * 8 + (g ^ (r & 7))) * 8]) = src;
      } else {
        int i0 = (ct - 3) * 32 + g * 4;
        bf16x8v v;
#pragma unroll
        for (int q = 0; q < 4; q++) {
          int i = i0 + q;
          float2 exy = cmul(tabX[xq * 64 + i], tabY[yq * 64 + i]);
          float2 e = cmul(exy, tabZ[r * 64 + i]);   // z == r (32-aligned block)
          v[q * 2]     = f2b(e.y);   // sin
          v[q * 2 + 1] = f2b(e.x);   // cos
        }
        *reinterpret_cast<bf16x8v*>(&A_lds[(r * 8 + (g ^ (r & 7))) * 8]) = v;
      }
    }
    {   // stage B chunk: 128 cols x 64 k
#pragma unroll
      for (int it = 0; it < 4; it++) {
        int u = it * 256 + t;
        int col = u >> 3, g = u & 7;
        const int4 src = *reinterpret_cast<const int4*>(
            Wqb_s + (size_t)col * 320 + ct * 64 + g * 8);
        *reinterpret_cast<int4*>(&B_lds[(col * 8 + (g ^ (col & 7))) * 8]) = src;
      }
    }
    __syncthreads();
#pragma unroll
    for (int ks = 0; ks < 2; ks++) {
      int kb = ks * 4 + (lane >> 4);
      bf16x8v a[2], bb[2];
#pragma unroll
      for (int m = 0; m < 2; m++) {
        int row = m * 16 + (lane & 15);
        a[m] = *reinterpret_cast<const bf16x8v*>(&A_lds[(row * 8 + (kb ^ (row & 7))) * 8]);
      }
#pragma unroll
      for (int f = 0; f < 2; f++) {
        int col = w * 32 + f * 16 + (lane & 15);
        bb[f] = *reinterpret_cast<const bf16x8v*>(&B_lds[(col * 8 + (kb ^ (col & 7))) * 8]);
      }
#pragma unroll
      for (int m = 0; m < 2; m++)
#pragma unroll
        for (int f = 0; f < 2; f++)
          acc[m][f] = __builtin_amdgcn_mfma_f32_16x16x32_bf16(a[m], bb[f], acc[m][f], 0, 0, 0);
    }
  }
  // epilogue: qh_lds = acc + qcb (bf16)
#pragma unroll
  for (int m = 0; m < 2; m++)
#pragma unroll
    for (int f = 0; f < 2; f++)
#pragma unroll
      for (int reg = 0; reg < 4; reg++) {
        int row = m * 16 + (lane >> 4) * 4 + reg;
        int col = w * 32 + f * 16 + (lane & 15);
        qh_lds[row * 128 + col] = f2b(acc[m][f][reg] + qcb[col]);
      }
  __syncthreads();

  // phase D: logits — octet-per-thread, bf16x8 loads, single shfl
  {
    const int oct = t & 15, rjIdx = t >> 4;
    const int c0 = oct * 8;
#pragma unroll
    for (int it = 0; it < 10; it++) {
      int rj = rjIdx + it * 16;
      int r = rj / J5;
      ushort4 I4 = *reinterpret_cast<const ushort4*>(sIr[rj]);
      float4 W4 = *reinterpret_cast<const float4*>(sW4[rj]);
      bf16x8v t0 = *reinterpret_cast<const bf16x8v*>(k2b + (size_t)I4.x * 128 + c0);
      bf16x8v t1 = *reinterpret_cast<const bf16x8v*>(k2b + (size_t)I4.y * 128 + c0);
      bf16x8v t2 = *reinterpret_cast<const bf16x8v*>(k2b + (size_t)I4.z * 128 + c0);
      bf16x8v t3 = *reinterpret_cast<const bf16x8v*>(k2b + (size_t)I4.w * 128 + c0);
      bf16x8v q8 = *reinterpret_cast<const bf16x8v*>(&qh_lds[r * 128 + c0]);
      float pv = 0.f;
#pragma unroll
      for (int e = 0; e < 8; e++) {
        float kh = fmaf(W4.x, b2f(t0[e]), fmaf(W4.y, b2f(t1[e]),
                   fmaf(W4.z, b2f(t2[e]), W4.w * b2f(t3[e]))));
        pv = fmaf(b2f(q8[e]), kh, pv);
      }
      pv += __shfl_xor(pv, 1);
      if (!(oct & 1)) lg[rj * 8 + (oct >> 1)] = pv * 0.25f;
    }
  }
  __syncthreads();

  // phase E: softmax over j per (r,h): 32*8 = 256 threads
  {
    int r = t >> 3, h = t & 7;
    float l[J5];
    float m = -1e30f;
#pragma unroll
    for (int j = 0; j < J5; j++) { l[j] = lg[(r * J5 + j) * 8 + h]; m = fmaxf(m, l[j]); }
    float sden = 0.f;
#pragma unroll
    for (int j = 0; j < J5; j++) { l[j] = expf(l[j] - m); sden += l[j]; }
    float inv = 1.0f / sden;
#pragma unroll
    for (int j = 0; j < J5; j++) lg[(r * J5 + j) * 8 + h] = l[j] * inv;
  }
  __syncthreads();

  // phase F: output — octet-per-thread accumulation, 2 rows/thread
  {
    const int oct = t & 15;
    const int c0 = oct * 8;
#pragma unroll
    for (int it = 0; it < 2; it++) {
      int r = (t >> 4) + it * 16;
      float o8[8] = {0.f, 0.f, 0.f, 0.f, 0.f, 0.f, 0.f, 0.f};
#pragma unroll
      for (int j = 0; j < J5; j++) {
        int rj = r * J5 + j;
        float aw = lg[rj * 8 + (oct >> 1)];
        ushort4 I4 = *reinterpret_cast<const ushort4*>(sIr[rj]);
        float4 W4 = *reinterpret_cast<const float4*>(sW4[rj]);
        float w0 = aw * W4.x, w1 = aw * W4.y, w2 = aw * W4.z, w3 = aw * W4.w;
        bf16x8v t0 = *reinterpret_cast<const bf16x8v*>(v2b + (size_t)I4.x * 128 + c0);
        bf16x8v t1 = *reinterpret_cast<const bf16x8v*>(v2b + (size_t)I4.y * 128 + c0);
        bf16x8v t2 = *reinterpret_cast<const bf16x8v*>(v2b + (size_t)I4.z * 128 + c0);
        bf16x8v t3 = *reinterpret_cast<const bf16x8v*>(v2b + (size_t)I4.w * 128 + c0);
#pragma unroll
        for (int e = 0; e < 8; e++) {
          o8[e] = fmaf(w0, b2f(t0[e]), o8[e]);
          o8[e] = fmaf(w1, b2f(t1[e]), o8[e]);
          o8[e] = fmaf(w2, b2f(t2[e]), o8[e]);
          o8[e] = fmaf(w3, b2f(t3[e]), o8[e]);
        }
      }
      bf16x8v out;
#pragma unroll
      for (int e = 0; e < 8; e++) out[e] = f2b(o8[e]);
      *reinterpret_cast<bf16x8v*>((short*)obuf + ((size_t)b * NVOX + n0 + r) * 128 + c0) = out;
    }
  }
}

// ---------- full-volume plane reductions (one pass) ----------
__global__ __launch_bounds__(128) void k_reduce(const bf16* __restrict__ obuf,
                                                float* __restrict__ pacc) {
  int blk = blockIdx.x;          // 0..767 ; 4 cells/block
  int b = blockIdx.y;
  int t = threadIdx.x;
  int quad = t & 31, sub = t >> 5;
  int c0 = quad * 4;
  int cell = blk * 4 + sub;      // 0..3071
  const ushort* ob = (const ushort*)obuf + (size_t)b * NVOX * 128;
  float4 acc = {0.f, 0.f, 0.f, 0.f};
  if (cell < 1024) {             // xz: row=z, col=x ; sum over y
    int z = cell >> 5, x = cell & 31;
    for (int y = 0; y < 32; y++) {
      ushort4 u = *(const ushort4*)(ob + ((size_t)(x * 1024 + y * 32 + z) * 128 + c0));
      acc.x += b2f((short)u.x); acc.y += b2f((short)u.y);
      acc.z += b2f((short)u.z); acc.w += b2f((short)u.w);
    }
    *(float4*)(&pacc[((size_t)(b * 96 + z) * 32 + x) * 128 + c0]) = acc;
  } else if (cell < 2048) {      // xy: row=y, col=x ; sum over z
    int e = cell - 1024;
    int y = e >> 5, x = e & 31;
    for (int z = 0; z < 32; z++) {
      ushort4 u = *(const ushort4*)(ob + ((size_t)(x * 1024 + y * 32 + z) * 128 + c0));
      acc.x += b2f((short)u.x); acc.y += b2f((short)u.y);
      acc.z += b2f((short)u.z); acc.w += b2f((short)u.w);
    }
    *(float4*)(&pacc[((size_t)(b * 96 + 32 + y) * 32 + x) * 128 + c0]) = acc;
  } else {                       // yz: row=z, col=y ; sum over x
    int e = cell - 2048;
    int z = e >> 5, y = e & 31;
    for (int x = 0; x < 32; x++) {
      ushort4 u = *(const ushort4*)(ob + ((size_t)(x * 1024 + y * 32 + z) * 128 + c0));
      acc.x += b2f((short)u.x); acc.y += b2f((short)u.y);
      acc.z += b2f((short)u.z); acc.w += b2f((short)u.w);
    }
    *(float4*)(&pacc[((size_t)(b * 96 + 64 + z) * 32 + y) * 128 + c0]) = acc;
  }
}

// ---------- final projection ----------
__global__ __launch_bounds__(128) void k_final(
    const float* __restrict__ pacc, const float* __restrict__ Wo,
    const float* __restrict__ obb, float* __restrict__ outp) {
  int bp = blockIdx.x;
  int b = bp / 96, prow = bp % 96;
  int obase = blockIdx.y * 16;
  __shared__ __align__(16) float lds[32 * 129];
  for (int idx = threadIdx.x; idx < 4096; idx += 128) {
    int col = idx >> 7, k = idx & 127;
    lds[col * 129 + k] = pacc[(size_t)bp * 32 * 128 + idx] * (1.0f / 32.0f);
  }
  __syncthreads();
  for (int e = threadIdx.x; e < 16 * 32; e += 128) {
    int o = obase + (e >> 5), col = e & 31;
    float val = obb[o];
    const float* wr = Wo + (size_t)o * 128;
    const float* lr = lds + col * 129;
    for (int k = 0; k < 128; k++) val = fmaf(wr[k], lr[k], val);
    outp[((size_t)(b * 64 + o) * 96 + prow) * 32 + col] = val;
  }
}

extern "C" void kernel_launch(void* const* d_in, const int* in_sizes, int n_in,
                              void* d_out, int out_size, void* d_ws, size_t ws_size,
                              hipStream_t stream) {
  const float* tp     = (const float*)d_in[0];
  const float* img    = (const float*)d_in[1];
  const float* proj   = (const float*)d_in[2];
  const float* k_w    = (const float*)d_in[4];
  const float* k_b    = (const float*)d_in[5];
  const float* q_w    = (const float*)d_in[6];
  const float* q_b    = (const float*)d_in[7];
  const float* v_w    = (const float*)d_in[8];
  const float* v_b    = (const float*)d_in[9];
  const float* in_w   = (const float*)d_in[10];
  const float* in_b   = (const float*)d_in[11];
  const float* out_w  = (const float*)d_in[12];
  const float* out_b  = (const float*)d_in[13];
  const float* proj_w = (const float*)d_in[14];
  const float* proj_b = (const float*)d_in[15];
  const int B = 2;

  // workspace layout (float slots); fills indicate ws_size = 256 MiB, guard below protects anyway
  float* ws = (float*)d_ws;
  size_t off = 0;
  short*  tri_tb = (short*)(ws + off);  off += 196608;   // 2*3*1024*64 bf16
  short*  Wkvb_s = (short*)(ws + off);  off += 163840;   // 256*1280 bf16
  short*  Wqb_s  = (short*)(ws + off);  off += 20480;    // 128*320 bf16
  float*  peb    = ws + off;            off += 65536;    // 2*256*128
  float2* tabs   = (float2*)(ws + off); off += 12288;    // 3*32*64 cplx
  float*  qcb    = ws + off;            off += 128;
  float*  Wo     = ws + off;            off += 8192;
  float*  obb    = ws + off;            off += 64;
  short*  k2b    = (short*)(ws + off);  off += 163840;   // 2560*128 bf16
  short*  v2b    = (short*)(ws + off);  off += 163840;
  float*  pacc   = ws + off;            off += 786432;   // 2*96*32*128
  float*  zone   = ws + off;            off += 4194304;  // max(imgb 1.6M, obuf 4.2M slots)
  short*  imgb   = (short*)zone;                         // 2560*1280 bf16 (early)
  bf16*   obuf   = (bf16*)zone;                          // 2*32768*128 bf16 (late)
  if (ws_size < off * sizeof(float)) return;  // ~23.1 MB needed; clean fail if short

  k_prep<<<dim3(NB_TOTAL), dim3(256), 0, stream>>>(
      img, tp, k_w, k_b, q_w, q_b, v_w, v_b, in_w, in_b, out_w, out_b, proj_w, proj_b,
      tabs, Wqb_s, Wo, qcb, obb, imgb, tri_tb, Wkvb_s, peb);
  k_gemm_kv<<<dim3(40, 4), dim3(256), 0, stream>>>(imgb, Wkvb_s, peb, k2b, v2b);
  k_main<<<dim3(NVOX / 32, B), dim3(256), 0, stream>>>(
      tri_tb, Wqb_s, qcb, tabs, k2b, v2b, proj, obuf);
  k_reduce<<<dim3(768, B), dim3(128), 0, stream>>>(obuf, pacc);
  k_final<<<dim3(B * 96, 4), dim3(128), 0, stream>>>(pacc, Wo, obb, (float*)d_out);
}